// Round 4
// baseline (1143.136 us; speedup 1.0000x reference)
//
#include <hip/hip_runtime.h>
#include <cstdint>

#define NN 50000
#define NE 800000
#define ET 64          // edges per block tile  (800000 = 64 * 12500, exact)
#define MS 148         // msg_in row stride in floats (592B, 16B-aligned, bank-friendly)
#define HS 132         // hidden row stride in floats (528B, 16B-aligned)

__device__ __forceinline__ float silu(float v) {
    return v / (1.0f + expf(-v));
}

// ---------------------------------------------------------------------------
// Edge kernel: msg = silu([x[src], x[dst], rbf] @ mw1 + mb1) @ mw2 + mb2
// then atomicAdd into agg[dst], and count into cnt[dst].
// ---------------------------------------------------------------------------
__global__ __launch_bounds__(256) void edge_kernel(
    const float* __restrict__ x,
    const int*   __restrict__ ei,      // [2][NE]
    const float* __restrict__ elen,    // [NE]
    const float* __restrict__ mw1,     // [144][128]
    const float* __restrict__ mb1,     // [128]
    const float* __restrict__ mw2,     // [128][64]
    const float* __restrict__ mb2,     // [64]
    float* __restrict__ agg,           // [NN][64]
    float* __restrict__ cnt)           // [NN]
{
    __shared__ float smem[ET * MS];    // msg tile, later reused as hidden tile
    __shared__ int   dst_s[ET];

    const int tid = threadIdx.x;
    const int e0  = blockIdx.x * ET;
    const int* __restrict__ src_idx = ei;
    const int* __restrict__ dst_idx = ei + NE;

    if (tid < ET) dst_s[tid] = dst_idx[e0 + tid];

    // ---- stage msg_in tile: [64 edges][144] = x[src](64) | x[dst](64) | rbf(16)
    // phases A/B: float4 gather. 64 edges * 16 float4 = 1024; 256 thr * 4 iters.
    #pragma unroll
    for (int i = 0; i < 4; ++i) {
        int idx = i * 256 + tid;
        int e   = idx >> 4;
        int c4  = idx & 15;
        int s   = src_idx[e0 + e];
        int d   = dst_idx[e0 + e];
        float4 vs = ((const float4*)(x + (size_t)s * 64))[c4];
        float4 vd = ((const float4*)(x + (size_t)d * 64))[c4];
        float* row = smem + e * MS;
        ((float4*)row)[c4]        = vs;   // row base 592B-aligned -> 16B ok
        ((float4*)(row + 64))[c4] = vd;   // +256B, still aligned
    }
    // phase C: rbf. 64 edges * 16 centers.
    #pragma unroll
    for (int i = 0; i < 4; ++i) {
        int idx = i * 256 + tid;
        int e   = idx >> 4;
        int c   = idx & 15;
        float dist = elen[e0 + e];
        float t = dist - (float)c * (10.0f / 15.0f);
        smem[e * MS + 128 + c] = expf(-t * t * 4.5f);
    }
    __syncthreads();

    // ---- layer 1: [64e x 144] @ [144 x 128].  thread = ey*16+hx
    // each thread: edges ey*4+0..3, hidden cols hx*8+0..7
    const int ey = tid >> 4;
    const int hx = tid & 15;

    float acc[4][8];
    #pragma unroll
    for (int q = 0; q < 8; ++q) {
        float b = mb1[hx * 8 + q];
        acc[0][q] = b; acc[1][q] = b; acc[2][q] = b; acc[3][q] = b;
    }

    #pragma unroll 4
    for (int k = 0; k < 144; ++k) {
        float4 wa = *(const float4*)(mw1 + k * 128 + hx * 8);
        float4 wb = *(const float4*)(mw1 + k * 128 + hx * 8 + 4);
        float wv[8] = {wa.x, wa.y, wa.z, wa.w, wb.x, wb.y, wb.z, wb.w};
        float mv[4];
        #pragma unroll
        for (int i = 0; i < 4; ++i) mv[i] = smem[(ey * 4 + i) * MS + k];
        #pragma unroll
        for (int i = 0; i < 4; ++i)
            #pragma unroll
            for (int q = 0; q < 8; ++q)
                acc[i][q] = fmaf(mv[i], wv[q], acc[i][q]);
    }

    __syncthreads();   // all msg reads done; smem reused for hidden

    // silu + write hidden tile [64e][128] at stride HS
    #pragma unroll
    for (int i = 0; i < 4; ++i) {
        float4 h0, h1;
        h0.x = silu(acc[i][0]); h0.y = silu(acc[i][1]);
        h0.z = silu(acc[i][2]); h0.w = silu(acc[i][3]);
        h1.x = silu(acc[i][4]); h1.y = silu(acc[i][5]);
        h1.z = silu(acc[i][6]); h1.w = silu(acc[i][7]);
        float* hrow = smem + (ey * 4 + i) * HS;
        ((float4*)hrow)[hx * 2]     = h0;
        ((float4*)hrow)[hx * 2 + 1] = h1;
    }
    __syncthreads();

    // ---- layer 2: [64e x 128] @ [128 x 64]. thread: edges ey*4+0..3, outs ox*4+0..3
    const int ox = hx;
    float a2[4][4];
    #pragma unroll
    for (int q = 0; q < 4; ++q) {
        float b = mb2[ox * 4 + q];
        a2[0][q] = b; a2[1][q] = b; a2[2][q] = b; a2[3][q] = b;
    }

    #pragma unroll 4
    for (int k = 0; k < 128; ++k) {
        float4 w4 = *(const float4*)(mw2 + k * 64 + ox * 4);
        float hv[4];
        #pragma unroll
        for (int i = 0; i < 4; ++i) hv[i] = smem[(ey * 4 + i) * HS + k];
        #pragma unroll
        for (int i = 0; i < 4; ++i) {
            a2[i][0] = fmaf(hv[i], w4.x, a2[i][0]);
            a2[i][1] = fmaf(hv[i], w4.y, a2[i][1]);
            a2[i][2] = fmaf(hv[i], w4.z, a2[i][2]);
            a2[i][3] = fmaf(hv[i], w4.w, a2[i][3]);
        }
    }

    // ---- scatter
    #pragma unroll
    for (int i = 0; i < 4; ++i) {
        int d = dst_s[ey * 4 + i];
        float* p = agg + (size_t)d * 64 + ox * 4;
        atomicAdd(p + 0, a2[i][0]);
        atomicAdd(p + 1, a2[i][1]);
        atomicAdd(p + 2, a2[i][2]);
        atomicAdd(p + 3, a2[i][3]);
    }
    if (tid < ET) atomicAdd(cnt + dst_s[tid], 1.0f);
}

// ---------------------------------------------------------------------------
// Node kernel: out = LN( silu([x, agg/max(cnt,1)] @ uw1 + ub1) @ uw2 + ub2 )
// 1 wave handles 4 nodes; lane j owns output channel j. 16 nodes per block.
// ---------------------------------------------------------------------------
__global__ __launch_bounds__(256) void node_kernel(
    const float* __restrict__ x,
    const float* __restrict__ agg,
    const float* __restrict__ cnt,
    const float* __restrict__ uw1,   // [128][64]
    const float* __restrict__ ub1,   // [64]
    const float* __restrict__ uw2,   // [64][64]
    const float* __restrict__ ub2,   // [64]
    const float* __restrict__ lng,
    const float* __restrict__ lnb,
    float* __restrict__ out)
{
    __shared__ float upd_s[4][4][132];  // [wave][node][128]
    __shared__ float h_s[4][4][68];     // [wave][node][64]

    const int lane = threadIdx.x & 63;
    const int wid  = threadIdx.x >> 6;
    const int nb   = blockIdx.x * 16 + wid * 4;   // 50000 = 16*3125, exact

    #pragma unroll
    for (int t = 0; t < 4; ++t) {
        int n = nb + t;
        upd_s[wid][t][lane] = x[(size_t)n * 64 + lane];
        float c = fmaxf(cnt[n], 1.0f);
        upd_s[wid][t][64 + lane] = agg[(size_t)n * 64 + lane] / c;
    }
    __syncthreads();

    float a1[4];
    #pragma unroll
    for (int t = 0; t < 4; ++t) a1[t] = ub1[lane];
    #pragma unroll 4
    for (int k = 0; k < 128; ++k) {
        float w = uw1[k * 64 + lane];
        #pragma unroll
        for (int t = 0; t < 4; ++t) a1[t] = fmaf(upd_s[wid][t][k], w, a1[t]);
    }
    #pragma unroll
    for (int t = 0; t < 4; ++t) h_s[wid][t][lane] = silu(a1[t]);
    __syncthreads();

    float a2[4];
    #pragma unroll
    for (int t = 0; t < 4; ++t) a2[t] = ub2[lane];
    #pragma unroll 4
    for (int k = 0; k < 64; ++k) {
        float w = uw2[k * 64 + lane];
        #pragma unroll
        for (int t = 0; t < 4; ++t) a2[t] = fmaf(h_s[wid][t][k], w, a2[t]);
    }

    float g = lng[lane], bb = lnb[lane];
    #pragma unroll
    for (int t = 0; t < 4; ++t) {
        float v = a2[t];
        float s = v;
        #pragma unroll
        for (int off = 32; off; off >>= 1) s += __shfl_xor(s, off);
        float mu = s * (1.0f / 64.0f);
        float d = v - mu;
        float sq = d * d;
        #pragma unroll
        for (int off = 32; off; off >>= 1) sq += __shfl_xor(sq, off);
        float var = sq * (1.0f / 64.0f);
        out[(size_t)(nb + t) * 64 + lane] = d * rsqrtf(var + 1e-5f) * g + bb;
    }
}

extern "C" void kernel_launch(void* const* d_in, const int* in_sizes, int n_in,
                              void* d_out, int out_size, void* d_ws, size_t ws_size,
                              hipStream_t stream) {
    const float* x    = (const float*)d_in[0];
    const int*   ei   = (const int*)  d_in[1];
    // d_in[2] = edge_vec (unused by reference)
    const float* elen = (const float*)d_in[3];
    const float* mw1  = (const float*)d_in[4];
    const float* mb1  = (const float*)d_in[5];
    const float* mw2  = (const float*)d_in[6];
    const float* mb2  = (const float*)d_in[7];
    const float* uw1  = (const float*)d_in[8];
    const float* ub1  = (const float*)d_in[9];
    const float* uw2  = (const float*)d_in[10];
    const float* ub2  = (const float*)d_in[11];
    const float* lng  = (const float*)d_in[12];
    const float* lnb  = (const float*)d_in[13];

    float* agg = (float*)d_ws;                 // [NN][64]
    float* cnt = agg + (size_t)NN * 64;        // [NN]

    hipMemsetAsync(d_ws, 0, (size_t)(NN * 64 + NN) * sizeof(float), stream);
    edge_kernel<<<NE / ET, 256, 0, stream>>>(x, ei, elen, mw1, mb1, mw2, mb2, agg, cnt);
    node_kernel<<<NN / 16, 256, 0, stream>>>(x, agg, cnt, uw1, ub1, uw2, ub2, lng, lnb,
                                             (float*)d_out);
}

// Round 5
// 899.575 us; speedup vs baseline: 1.2708x; 1.2708x over previous
//
#include <hip/hip_runtime.h>
#include <cstdint>

#define NN 50000
#define NE 800000
#define NT 12500        // edge tiles of 64 (800000 = 64*12500 exact)
#define MSW 168         // msg LDS row stride, bf16 elems (336B -> 2-way banks, free)
#define HSW 136         // hidden LDS row stride (272B -> 2-way banks, free)

typedef short short8 __attribute__((ext_vector_type(8)));
typedef float f32x4  __attribute__((ext_vector_type(4)));

__device__ __forceinline__ ushort f2bf(float f) {
    union { float f; uint u; } v; v.f = f;
    return (ushort)((v.u + 0x7FFFu + ((v.u >> 16) & 1u)) >> 16);   // RNE
}
__device__ __forceinline__ float silu(float v) { return v / (1.0f + expf(-v)); }

// ---- prep: x (f32 [NN][64]) -> bf16 ----------------------------------------
__global__ __launch_bounds__(256) void conv_x(const float* __restrict__ x,
                                              ushort* __restrict__ xb) {
    int i = blockIdx.x * 256 + threadIdx.x;      // over 800000 float4s
    float4 v = ((const float4*)x)[i];
    uint2 o;
    o.x = (uint)f2bf(v.x) | ((uint)f2bf(v.y) << 16);
    o.y = (uint)f2bf(v.z) | ((uint)f2bf(v.w) << 16);
    ((uint2*)xb)[i] = o;
}

// ---- prep: weights -> bf16, transposed, K zero-padded 144->160 -------------
// w1t: [128 hidden][160 k], w2t: [64 out][128 k]
__global__ __launch_bounds__(256) void conv_w(const float* __restrict__ mw1,
                                              const float* __restrict__ mw2,
                                              ushort* __restrict__ w1t,
                                              ushort* __restrict__ w2t) {
    int i = blockIdx.x * 256 + threadIdx.x;      // 112*256 = 28672 = 20480+8192
    if (i < 128 * 160) {
        int h = i / 160, k = i % 160;
        w1t[i] = f2bf(k < 144 ? mw1[k * 128 + h] : 0.0f);
    } else {
        int j = i - 128 * 160;
        int o = j / 128, k = j % 128;
        w2t[j] = f2bf(mw2[k * 64 + o]);
    }
}

// ---------------------------------------------------------------------------
// Edge kernel (MFMA, both layers transposed):
//   C1'[hidden][edge] = W1T @ msg^T ; H[e][h] = silu(C1') (bf16, LDS)
//   C2'[out][edge]    = W2T @ H^T   ; atomic scatter into agg[dst]
// ---------------------------------------------------------------------------
__global__ __launch_bounds__(256) void edge_mfma(
    const ushort* __restrict__ xb,    // [NN][64] bf16
    const int*    __restrict__ ei,    // [2][NE]
    const float*  __restrict__ elen,  // [NE]
    const ushort* __restrict__ w1t,   // [128][160] bf16
    const float*  __restrict__ mb1,   // [128]
    const ushort* __restrict__ w2t,   // [64][128] bf16
    const float*  __restrict__ mb2,   // [64]
    float* __restrict__ agg,          // [NN][64]
    float* __restrict__ cnt)          // [NN]
{
    __shared__ ushort msg_s[64 * MSW];   // 21504 B
    __shared__ ushort h_s[64 * HSW];     // 17408 B
    __shared__ int    dst_sh[64];

    const int tid  = threadIdx.x;
    const int wv   = tid >> 6;
    const int lane = tid & 63;
    const int l16  = lane & 15;
    const int g    = lane >> 4;

    // persistent weight fragments (A-operands): lane -> A[m=l16][k=g*8+j]
    short8 a1[2][5];
    #pragma unroll
    for (int m = 0; m < 2; ++m)
        #pragma unroll
        for (int kk = 0; kk < 5; ++kk)
            a1[m][kk] = *(const short8*)(w1t + (wv*32 + m*16 + l16)*160 + kk*32 + g*8);
    short8 a2[4];
    #pragma unroll
    for (int kk = 0; kk < 4; ++kk)
        a2[kk] = *(const short8*)(w2t + (wv*16 + l16)*128 + kk*32 + g*8);
    float b1v[2][4], b2v[4];
    #pragma unroll
    for (int m = 0; m < 2; ++m)
        #pragma unroll
        for (int r = 0; r < 4; ++r)
            b1v[m][r] = mb1[wv*32 + m*16 + g*4 + r];
    #pragma unroll
    for (int r = 0; r < 4; ++r)
        b2v[r] = mb2[wv*16 + g*4 + r];

    // zero the K-pad columns 144..159 once (never touched again)
    {
        int e = tid >> 2, q = tid & 3;
        *(uint2*)&msg_s[e * MSW + 144 + q * 4] = make_uint2(0u, 0u);
    }

    for (int t = blockIdx.x; t < NT; t += gridDim.x) {
        const int e0 = t * 64;

        // ---- stage x[src] | x[dst] as bf16 (16B per thread-iter)
        #pragma unroll
        for (int i = 0; i < 4; ++i) {
            int idx  = i * 256 + tid;
            int half = idx >> 9;            // 0: src, 1: dst
            int e    = (idx >> 3) & 63;
            int c    = idx & 7;
            int n    = ei[half * NE + e0 + e];
            uint4 v  = *(const uint4*)(xb + (size_t)n * 64 + c * 8);
            *(uint4*)&msg_s[e * MSW + half * 64 + c * 8] = v;
        }
        // ---- rbf (2 centers per thread-iter, packed b32 write)
        #pragma unroll
        for (int i = 0; i < 2; ++i) {
            int idx = i * 256 + tid;
            int e   = idx >> 3, p = idx & 7;
            float dist = elen[e0 + e];
            float u0 = dist - (float)(2 * p)     * (10.0f / 15.0f);
            float u1 = dist - (float)(2 * p + 1) * (10.0f / 15.0f);
            uint pk = (uint)f2bf(expf(-u0 * u0 * 4.5f))
                    | ((uint)f2bf(expf(-u1 * u1 * 4.5f)) << 16);
            *(uint*)&msg_s[e * MSW + 128 + p * 2] = pk;
        }
        if (tid < 64) dst_sh[tid] = ei[NE + e0 + tid];
        __syncthreads();                                    // sync1

        // latch dst to regs (dst_sh is overwritten next iter before a barrier)
        int dvals[4];
        #pragma unroll
        for (int nt = 0; nt < 4; ++nt) dvals[nt] = dst_sh[nt * 16 + l16];
        int dmine = dst_sh[lane & 63];                      // for cnt (tid<64 uses it)

        // ---- layer 1: C1'[hidden][edge], M=32/wave, N=64, K=160
        f32x4 c1[2][4];
        #pragma unroll
        for (int m = 0; m < 2; ++m)
            #pragma unroll
            for (int nt = 0; nt < 4; ++nt)
                c1[m][nt] = (f32x4){b1v[m][0], b1v[m][1], b1v[m][2], b1v[m][3]};
        #pragma unroll
        for (int nt = 0; nt < 4; ++nt)
            #pragma unroll
            for (int kk = 0; kk < 5; ++kk) {
                short8 b = *(const short8*)&msg_s[(nt*16 + l16)*MSW + kk*32 + g*8];
                c1[0][nt] = __builtin_amdgcn_mfma_f32_16x16x32_bf16(a1[0][kk], b, c1[0][nt], 0, 0, 0);
                c1[1][nt] = __builtin_amdgcn_mfma_f32_16x16x32_bf16(a1[1][kk], b, c1[1][nt], 0, 0, 0);
            }

        // ---- silu -> H[e][h] bf16 (4 consecutive h per lane -> b64 write)
        #pragma unroll
        for (int m = 0; m < 2; ++m)
            #pragma unroll
            for (int nt = 0; nt < 4; ++nt) {
                uint2 pk;
                pk.x = (uint)f2bf(silu(c1[m][nt][0])) | ((uint)f2bf(silu(c1[m][nt][1])) << 16);
                pk.y = (uint)f2bf(silu(c1[m][nt][2])) | ((uint)f2bf(silu(c1[m][nt][3])) << 16);
                *(uint2*)&h_s[(nt*16 + l16)*HSW + wv*32 + m*16 + g*4] = pk;
            }
        __syncthreads();                                    // sync2

        // ---- layer 2: C2'[out][edge], M=16/wave, N=64, K=128
        f32x4 c2[4];
        #pragma unroll
        for (int nt = 0; nt < 4; ++nt)
            c2[nt] = (f32x4){b2v[0], b2v[1], b2v[2], b2v[3]};
        #pragma unroll
        for (int nt = 0; nt < 4; ++nt)
            #pragma unroll
            for (int kk = 0; kk < 4; ++kk) {
                short8 b = *(const short8*)&h_s[(nt*16 + l16)*HSW + kk*32 + g*8];
                c2[nt] = __builtin_amdgcn_mfma_f32_16x16x32_bf16(a2[kk], b, c2[nt], 0, 0, 0);
            }

        // ---- scatter (4 consecutive out-channels per lane per edge)
        #pragma unroll
        for (int nt = 0; nt < 4; ++nt) {
            float* p = agg + (size_t)dvals[nt] * 64 + wv*16 + g*4;
            atomicAdd(p + 0, c2[nt][0]);
            atomicAdd(p + 1, c2[nt][1]);
            atomicAdd(p + 2, c2[nt][2]);
            atomicAdd(p + 3, c2[nt][3]);
        }
        if (tid < 64) atomicAdd(cnt + dmine, 1.0f);
    }
}

// ---------------------------------------------------------------------------
// Node kernel (unchanged fp32): out = LN(silu([x, agg/cnt] @ uw1 + ub1) @ uw2 + ub2)
// ---------------------------------------------------------------------------
__global__ __launch_bounds__(256) void node_kernel(
    const float* __restrict__ x,
    const float* __restrict__ agg,
    const float* __restrict__ cnt,
    const float* __restrict__ uw1,
    const float* __restrict__ ub1,
    const float* __restrict__ uw2,
    const float* __restrict__ ub2,
    const float* __restrict__ lng,
    const float* __restrict__ lnb,
    float* __restrict__ out)
{
    __shared__ float upd_s[4][4][132];
    __shared__ float h_s[4][4][68];

    const int lane = threadIdx.x & 63;
    const int wid  = threadIdx.x >> 6;
    const int nb   = blockIdx.x * 16 + wid * 4;

    #pragma unroll
    for (int t = 0; t < 4; ++t) {
        int n = nb + t;
        upd_s[wid][t][lane] = x[(size_t)n * 64 + lane];
        float c = fmaxf(cnt[n], 1.0f);
        upd_s[wid][t][64 + lane] = agg[(size_t)n * 64 + lane] / c;
    }
    __syncthreads();

    float a1[4];
    #pragma unroll
    for (int t = 0; t < 4; ++t) a1[t] = ub1[lane];
    #pragma unroll 4
    for (int k = 0; k < 128; ++k) {
        float w = uw1[k * 64 + lane];
        #pragma unroll
        for (int t = 0; t < 4; ++t) a1[t] = fmaf(upd_s[wid][t][k], w, a1[t]);
    }
    #pragma unroll
    for (int t = 0; t < 4; ++t) h_s[wid][t][lane] = silu(a1[t]);
    __syncthreads();

    float a2[4];
    #pragma unroll
    for (int t = 0; t < 4; ++t) a2[t] = ub2[lane];
    #pragma unroll 4
    for (int k = 0; k < 64; ++k) {
        float w = uw2[k * 64 + lane];
        #pragma unroll
        for (int t = 0; t < 4; ++t) a2[t] = fmaf(h_s[wid][t][k], w, a2[t]);
    }

    float gga = lng[lane], bb = lnb[lane];
    #pragma unroll
    for (int t = 0; t < 4; ++t) {
        float v = a2[t];
        float s = v;
        #pragma unroll
        for (int off = 32; off; off >>= 1) s += __shfl_xor(s, off);
        float mu = s * (1.0f / 64.0f);
        float d = v - mu;
        float sq = d * d;
        #pragma unroll
        for (int off = 32; off; off >>= 1) sq += __shfl_xor(sq, off);
        float var = sq * (1.0f / 64.0f);
        out[(size_t)(nb + t) * 64 + lane] = d * rsqrtf(var + 1e-5f) * gga + bb;
    }
}

extern "C" void kernel_launch(void* const* d_in, const int* in_sizes, int n_in,
                              void* d_out, int out_size, void* d_ws, size_t ws_size,
                              hipStream_t stream) {
    const float* x    = (const float*)d_in[0];
    const int*   ei   = (const int*)  d_in[1];
    // d_in[2] = edge_vec (unused by reference)
    const float* elen = (const float*)d_in[3];
    const float* mw1  = (const float*)d_in[4];
    const float* mb1  = (const float*)d_in[5];
    const float* mw2  = (const float*)d_in[6];
    const float* mb2  = (const float*)d_in[7];
    const float* uw1  = (const float*)d_in[8];
    const float* ub1  = (const float*)d_in[9];
    const float* uw2  = (const float*)d_in[10];
    const float* ub2  = (const float*)d_in[11];
    const float* lng  = (const float*)d_in[12];
    const float* lnb  = (const float*)d_in[13];

    // ws layout (bytes): agg[12.8M] | cnt[200K] | xb[6.4M] | w1t[40960] | w2t[16384]
    char* ws   = (char*)d_ws;
    float* agg = (float*)ws;
    float* cnt = (float*)(ws + 12800000);
    ushort* xb  = (ushort*)(ws + 13000000);
    ushort* w1t = (ushort*)(ws + 19400000);
    ushort* w2t = (ushort*)(ws + 19440960);

    hipMemsetAsync(d_ws, 0, 13000000, stream);
    conv_x<<<3125, 256, 0, stream>>>(x, xb);
    conv_w<<<112, 256, 0, stream>>>(mw1, mw2, w1t, w2t);
    edge_mfma<<<1024, 256, 0, stream>>>(xb, ei, elen, w1t, mb1, w2t, mb2, agg, cnt);
    node_kernel<<<NN / 16, 256, 0, stream>>>(x, agg, cnt, uw1, ub1, uw2, ub2, lng, lnb,
                                             (float*)d_out);
}

// Round 8
// 523.771 us; speedup vs baseline: 2.1825x; 1.7175x over previous
//
#include <hip/hip_runtime.h>
#include <cstdint>

#define NN 50000
#define NE 800000
#define NT 12500        // edge tiles of 64
#define NBLK 1024       // edge kernel blocks (contiguous tile chunks)
#define MSW 168         // msg LDS row stride, bf16 elems
#define HSW 136         // hidden LDS row stride

typedef short short8 __attribute__((ext_vector_type(8)));
typedef float f32x4  __attribute__((ext_vector_type(4)));

__device__ __forceinline__ ushort f2bf(float f) {
    union { float f; uint u; } v; v.f = f;
    return (ushort)((v.u + 0x7FFFu + ((v.u >> 16) & 1u)) >> 16);   // RNE
}
__device__ __forceinline__ float silu(float v) { return v / (1.0f + expf(-v)); }

// ---- prep: x -> bf16 -------------------------------------------------------
__global__ __launch_bounds__(256) void conv_x(const float* __restrict__ x,
                                              ushort* __restrict__ xb) {
    int i = blockIdx.x * 256 + threadIdx.x;      // 800000 float4s exact
    float4 v = ((const float4*)x)[i];
    uint2 o;
    o.x = (uint)f2bf(v.x) | ((uint)f2bf(v.y) << 16);
    o.y = (uint)f2bf(v.z) | ((uint)f2bf(v.w) << 16);
    ((uint2*)xb)[i] = o;
}

// ---- prep: weights -> bf16 transposed, K 144->160 zero-pad -----------------
__global__ __launch_bounds__(256) void conv_w(const float* __restrict__ mw1,
                                              const float* __restrict__ mw2,
                                              ushort* __restrict__ w1t,
                                              ushort* __restrict__ w2t) {
    int i = blockIdx.x * 256 + threadIdx.x;      // 112*256 = 28672
    if (i < 128 * 160) {
        int h = i / 160, k = i % 160;
        w1t[i] = f2bf(k < 144 ? mw1[k * 128 + h] : 0.0f);
    } else {
        int j = i - 128 * 160;
        int o = j / 128, k = j % 128;
        w2t[j] = f2bf(mw2[k * 64 + o]);
    }
}

// ---- counting sort by dst --------------------------------------------------
__global__ __launch_bounds__(256) void hist_k(const int* __restrict__ ei,
                                              int* __restrict__ hist) {
    int i = blockIdx.x * 256 + threadIdx.x;      // 800000 exact
    atomicAdd(&hist[ei[NE + i]], 1);
}

__global__ __launch_bounds__(256) void scan1(const int* __restrict__ hist,
                                             int* __restrict__ starts,
                                             int* __restrict__ bsum) {
    __shared__ int s[256];
    int t = threadIdx.x, b = blockIdx.x, i = b * 256 + t;
    int v = (i < NN) ? hist[i] : 0;
    s[t] = v; __syncthreads();
    #pragma unroll
    for (int off = 1; off < 256; off <<= 1) {
        int a = (t >= off) ? s[t - off] : 0;
        __syncthreads();
        s[t] += a;
        __syncthreads();
    }
    if (i < NN) starts[i] = s[t] - v;            // block-local exclusive
    if (t == 255) bsum[b] = s[255];
}

__global__ __launch_bounds__(256) void scan2(int* __restrict__ bsum) {
    __shared__ int s[256];
    int t = threadIdx.x;
    int v = (t < 196) ? bsum[t] : 0;
    s[t] = v; __syncthreads();
    #pragma unroll
    for (int off = 1; off < 256; off <<= 1) {
        int a = (t >= off) ? s[t - off] : 0;
        __syncthreads();
        s[t] += a;
        __syncthreads();
    }
    if (t < 196) bsum[t] = s[t] - v;             // exclusive, in place
}

__global__ __launch_bounds__(256) void scan3(int* __restrict__ starts,
                                             const int* __restrict__ bsum) {
    int i = blockIdx.x * 256 + threadIdx.x;
    if (i < NN) starts[i] += bsum[blockIdx.x];
}

__global__ __launch_bounds__(256) void rank_k(const int* __restrict__ ei,
                                              int* __restrict__ cursor,
                                              int* __restrict__ sortidx) {
    int e = blockIdx.x * 256 + threadIdx.x;      // 800000 exact
    int d = ei[NE + e];
    int pos = atomicAdd(&cursor[d], 1);
    sortidx[pos] = e;
}

// ---------------------------------------------------------------------------
// Edge kernel: sorted edges, MFMA both layers transposed, segmented-scan
// pre-reduction, tail-lane atomics into agg[dst].
// ---------------------------------------------------------------------------
__global__ __launch_bounds__(256) void edge_mfma(
    const ushort* __restrict__ xb,      // [NN][64] bf16
    const int*    __restrict__ sortidx, // [NE]
    const int*    __restrict__ ei,      // [2][NE]
    const float*  __restrict__ elen,    // [NE]
    const ushort* __restrict__ w1t,     // [128][160]
    const float*  __restrict__ mb1,
    const ushort* __restrict__ w2t,     // [64][128]
    const float*  __restrict__ mb2,
    float* __restrict__ agg)            // [NN][64]
{
    __shared__ ushort msg_s[64 * MSW];
    __shared__ ushort h_s[64 * HSW];

    const int tid  = threadIdx.x;
    const int wv   = tid >> 6;
    const int lane = tid & 63;
    const int l16  = lane & 15;
    const int g    = lane >> 4;

    // persistent weight fragments
    short8 a1[2][5];
    #pragma unroll
    for (int m = 0; m < 2; ++m)
        #pragma unroll
        for (int kk = 0; kk < 5; ++kk)
            a1[m][kk] = *(const short8*)(w1t + (wv*32 + m*16 + l16)*160 + kk*32 + g*8);
    short8 a2[4];
    #pragma unroll
    for (int kk = 0; kk < 4; ++kk)
        a2[kk] = *(const short8*)(w2t + (wv*16 + l16)*128 + kk*32 + g*8);
    float b1v[2][4], b2v[4];
    #pragma unroll
    for (int m = 0; m < 2; ++m)
        #pragma unroll
        for (int r = 0; r < 4; ++r)
            b1v[m][r] = mb1[wv*32 + m*16 + g*4 + r];
    #pragma unroll
    for (int r = 0; r < 4; ++r)
        b2v[r] = mb2[wv*16 + g*4 + r];

    // zero K-pad columns 144..159 once
    {
        int e = tid >> 2, qq = tid & 3;
        *(uint2*)&msg_s[e * MSW + 144 + qq * 4] = make_uint2(0u, 0u);
    }

    // contiguous tile chunk per block -> this block's atomics hit a small
    // consecutive agg range (stays in own XCD L2)
    const int q  = NT / NBLK, r = NT % NBLK;       // 12, 212
    const int t0 = blockIdx.x < r ? blockIdx.x * (q + 1)
                                  : r * (q + 1) + (blockIdx.x - r) * q;
    const int tn = blockIdx.x < r ? q + 1 : q;

    for (int tt = 0; tt < tn; ++tt) {
        const int e0 = (t0 + tt) * 64;

        // ---- stage x[src] | x[dst] (sorted order) as bf16
        #pragma unroll
        for (int i = 0; i < 4; ++i) {
            int idx  = i * 256 + tid;
            int half = idx >> 9;
            int e    = (idx >> 3) & 63;
            int c    = idx & 7;
            int se   = sortidx[e0 + e];
            int n    = ei[half * NE + se];
            uint4 v  = *(const uint4*)(xb + (size_t)n * 64 + c * 8);
            *(uint4*)&msg_s[e * MSW + half * 64 + c * 8] = v;
        }
        // ---- rbf
        #pragma unroll
        for (int i = 0; i < 2; ++i) {
            int idx = i * 256 + tid;
            int e   = idx >> 3, p = idx & 7;
            float dist = elen[sortidx[e0 + e]];
            float u0 = dist - (float)(2 * p)     * (10.0f / 15.0f);
            float u1 = dist - (float)(2 * p + 1) * (10.0f / 15.0f);
            uint pk = (uint)f2bf(expf(-u0 * u0 * 4.5f))
                    | ((uint)f2bf(expf(-u1 * u1 * 4.5f)) << 16);
            *(uint*)&msg_s[e * MSW + 128 + p * 2] = pk;
        }
        // per-lane dst for the 4 edge sub-tiles (sorted ascending)
        int dvals[4];
        #pragma unroll
        for (int nt = 0; nt < 4; ++nt)
            dvals[nt] = ei[NE + sortidx[e0 + nt * 16 + l16]];
        __syncthreads();                                    // sync1

        // ---- layer 1: C1'[hidden][edge]
        f32x4 c1[2][4];
        #pragma unroll
        for (int m = 0; m < 2; ++m)
            #pragma unroll
            for (int nt = 0; nt < 4; ++nt)
                c1[m][nt] = (f32x4){b1v[m][0], b1v[m][1], b1v[m][2], b1v[m][3]};
        #pragma unroll
        for (int nt = 0; nt < 4; ++nt)
            #pragma unroll
            for (int kk = 0; kk < 5; ++kk) {
                short8 b = *(const short8*)&msg_s[(nt*16 + l16)*MSW + kk*32 + g*8];
                c1[0][nt] = __builtin_amdgcn_mfma_f32_16x16x32_bf16(a1[0][kk], b, c1[0][nt], 0, 0, 0);
                c1[1][nt] = __builtin_amdgcn_mfma_f32_16x16x32_bf16(a1[1][kk], b, c1[1][nt], 0, 0, 0);
            }

        // ---- silu -> H[e][h] bf16
        #pragma unroll
        for (int m = 0; m < 2; ++m)
            #pragma unroll
            for (int nt = 0; nt < 4; ++nt) {
                uint2 pk;
                pk.x = (uint)f2bf(silu(c1[m][nt][0])) | ((uint)f2bf(silu(c1[m][nt][1])) << 16);
                pk.y = (uint)f2bf(silu(c1[m][nt][2])) | ((uint)f2bf(silu(c1[m][nt][3])) << 16);
                *(uint2*)&h_s[(nt*16 + l16)*HSW + wv*32 + m*16 + g*4] = pk;
            }
        __syncthreads();                                    // sync2

        // ---- layer 2: C2'[out][edge]
        f32x4 c2[4];
        #pragma unroll
        for (int nt = 0; nt < 4; ++nt)
            c2[nt] = (f32x4){b2v[0], b2v[1], b2v[2], b2v[3]};
        #pragma unroll
        for (int nt = 0; nt < 4; ++nt)
            #pragma unroll
            for (int kk = 0; kk < 4; ++kk) {
                short8 b = *(const short8*)&h_s[(nt*16 + l16)*HSW + kk*32 + g*8];
                c2[nt] = __builtin_amdgcn_mfma_f32_16x16x32_bf16(a2[kk], b, c2[nt], 0, 0, 0);
            }

        // ---- segmented reduce over equal-dst runs (16-lane clusters), then
        //      tail-lane atomics. 4 channel values per lane.
        #pragma unroll
        for (int nt = 0; nt < 4; ++nt) {
            int d  = dvals[nt];
            int dp = __shfl_up(d, 1, 16);
            int f  = (l16 == 0 || d != dp) ? 1 : 0;
            float v0 = c2[nt][0], v1 = c2[nt][1], v2 = c2[nt][2], v3 = c2[nt][3];
            #pragma unroll
            for (int off = 1; off < 16; off <<= 1) {
                float w0 = __shfl_up(v0, off, 16);
                float w1 = __shfl_up(v1, off, 16);
                float w2 = __shfl_up(v2, off, 16);
                float w3 = __shfl_up(v3, off, 16);
                int   ff = __shfl_up(f,  off, 16);
                if (l16 >= off && !f) { v0 += w0; v1 += w1; v2 += w2; v3 += w3; }
                if (l16 >= off) f |= ff;
            }
            int dn = __shfl_down(d, 1, 16);
            if (l16 == 15 || d != dn) {            // segment tail: full run sum
                float* p = agg + (size_t)d * 64 + wv * 16 + g * 4;
                atomicAdd(p + 0, v0);
                atomicAdd(p + 1, v1);
                atomicAdd(p + 2, v2);
                atomicAdd(p + 3, v3);
            }
        }
    }
}

// ---------------------------------------------------------------------------
// Node kernel (cnt now comes from the int histogram)
// ---------------------------------------------------------------------------
__global__ __launch_bounds__(256) void node_kernel(
    const float* __restrict__ x,
    const float* __restrict__ agg,
    const int*   __restrict__ hist,
    const float* __restrict__ uw1,
    const float* __restrict__ ub1,
    const float* __restrict__ uw2,
    const float* __restrict__ ub2,
    const float* __restrict__ lng,
    const float* __restrict__ lnb,
    float* __restrict__ out)
{
    __shared__ float upd_s[4][4][132];
    __shared__ float h_s[4][4][68];

    const int lane = threadIdx.x & 63;
    const int wid  = threadIdx.x >> 6;
    const int nb   = blockIdx.x * 16 + wid * 4;

    #pragma unroll
    for (int t = 0; t < 4; ++t) {
        int n = nb + t;
        upd_s[wid][t][lane] = x[(size_t)n * 64 + lane];
        float c = fmaxf((float)hist[n], 1.0f);
        upd_s[wid][t][64 + lane] = agg[(size_t)n * 64 + lane] / c;
    }
    __syncthreads();

    float a1[4];
    #pragma unroll
    for (int t = 0; t < 4; ++t) a1[t] = ub1[lane];
    #pragma unroll 4
    for (int k = 0; k < 128; ++k) {
        float w = uw1[k * 64 + lane];
        #pragma unroll
        for (int t = 0; t < 4; ++t) a1[t] = fmaf(upd_s[wid][t][k], w, a1[t]);
    }
    #pragma unroll
    for (int t = 0; t < 4; ++t) h_s[wid][t][lane] = silu(a1[t]);
    __syncthreads();

    float a2[4];
    #pragma unroll
    for (int t = 0; t < 4; ++t) a2[t] = ub2[lane];
    #pragma unroll 4
    for (int k = 0; k < 64; ++k) {
        float w = uw2[k * 64 + lane];
        #pragma unroll
        for (int t = 0; t < 4; ++t) a2[t] = fmaf(h_s[wid][t][k], w, a2[t]);
    }

    float gga = lng[lane], bb = lnb[lane];
    #pragma unroll
    for (int t = 0; t < 4; ++t) {
        float v = a2[t];
        float s = v;
        #pragma unroll
        for (int off = 32; off; off >>= 1) s += __shfl_xor(s, off);
        float mu = s * (1.0f / 64.0f);
        float d = v - mu;
        float sq = d * d;
        #pragma unroll
        for (int off = 32; off; off >>= 1) sq += __shfl_xor(sq, off);
        float var = sq * (1.0f / 64.0f);
        out[(size_t)(nb + t) * 64 + lane] = d * rsqrtf(var + 1e-5f) * gga + bb;
    }
}

extern "C" void kernel_launch(void* const* d_in, const int* in_sizes, int n_in,
                              void* d_out, int out_size, void* d_ws, size_t ws_size,
                              hipStream_t stream) {
    const float* x    = (const float*)d_in[0];
    const int*   ei   = (const int*)  d_in[1];
    const float* elen = (const float*)d_in[3];
    const float* mw1  = (const float*)d_in[4];
    const float* mb1  = (const float*)d_in[5];
    const float* mw2  = (const float*)d_in[6];
    const float* mb2  = (const float*)d_in[7];
    const float* uw1  = (const float*)d_in[8];
    const float* ub1  = (const float*)d_in[9];
    const float* uw2  = (const float*)d_in[10];
    const float* ub2  = (const float*)d_in[11];
    const float* lng  = (const float*)d_in[12];
    const float* lnb  = (const float*)d_in[13];

    // ws layout (bytes):
    // agg 0..12.8M | hist 12.8M | starts 13.0M | cursor 13.2M | sortidx 13.4M
    // | xb 16.6M | w1t 23.0M | w2t 23.04M   (total ~23.06 MB)
    char*  ws      = (char*)d_ws;
    float* agg     = (float*)ws;
    int*   hist    = (int*)(ws + 12800000);
    int*   starts  = (int*)(ws + 13000000);
    int*   cursor  = (int*)(ws + 13200000);
    int*   sortidx = (int*)(ws + 13400000);
    ushort* xb  = (ushort*)(ws + 16600000);
    ushort* w1t = (ushort*)(ws + 23000000);
    ushort* w2t = (ushort*)(ws + 23040960);

    hipMemsetAsync(d_ws, 0, 13000000, stream);           // agg + hist
    conv_x<<<3125, 256, 0, stream>>>(x, xb);
    conv_w<<<112, 256, 0, stream>>>(mw1, mw2, w1t, w2t);
    hist_k<<<3125, 256, 0, stream>>>(ei, hist);
    scan1<<<196, 256, 0, stream>>>(hist, starts, cursor);   // cursor <- block sums
    scan2<<<1, 256, 0, stream>>>(cursor);                   // exclusive-scan sums
    scan3<<<196, 256, 0, stream>>>(starts, cursor);         // final starts
    hipMemcpyAsync(cursor, starts, 200000, hipMemcpyDeviceToDevice, stream);
    rank_k<<<3125, 256, 0, stream>>>(ei, cursor, sortidx);
    edge_mfma<<<NBLK, 256, 0, stream>>>(xb, sortidx, ei, elen, w1t, mb1, w2t, mb2, agg);
    node_kernel<<<NN / 16, 256, 0, stream>>>(x, agg, hist, uw1, ub1, uw2, ub2, lng, lnb,
                                             (float*)d_out);
}

// Round 9
// 455.318 us; speedup vs baseline: 2.5106x; 1.1503x over previous
//
#include <hip/hip_runtime.h>
#include <cstdint>

#define NN 50000
#define NE 800000
#define NT 12500        // edge tiles of 64
#define NBLK 1024       // edge kernel blocks (contiguous tile chunks)
#define MSW 168         // msg LDS row stride, bf16 elems
#define HSW 136         // hidden LDS row stride
#define UPS 136         // node upd LDS stride (bf16)
#define HBS 72          // node hidden LDS stride (bf16)
#define OS  68          // node out LDS stride (f32)

typedef short short8 __attribute__((ext_vector_type(8)));
typedef float f32x4  __attribute__((ext_vector_type(4)));

__device__ __forceinline__ ushort f2bf(float f) {
    union { float f; uint u; } v; v.f = f;
    return (ushort)((v.u + 0x7FFFu + ((v.u >> 16) & 1u)) >> 16);   // RNE
}
__device__ __forceinline__ float silu(float v) { return v / (1.0f + expf(-v)); }

// ---- prep: x -> bf16, fused with dst histogram (both 800K tasks) -----------
__global__ __launch_bounds__(256) void conv_x_hist(const float* __restrict__ x,
                                                   const int* __restrict__ ei,
                                                   ushort* __restrict__ xb,
                                                   int* __restrict__ hist) {
    int i = blockIdx.x * 256 + threadIdx.x;      // 800000 exact
    float4 v = ((const float4*)x)[i];
    uint2 o;
    o.x = (uint)f2bf(v.x) | ((uint)f2bf(v.y) << 16);
    o.y = (uint)f2bf(v.z) | ((uint)f2bf(v.w) << 16);
    ((uint2*)xb)[i] = o;
    atomicAdd(&hist[ei[NE + i]], 1);
}

// ---- prep: all four weights -> bf16 transposed -----------------------------
// w1t[128][160] (K-pad), w2t[64][128], uw1t[64][128], uw2t[64][64]
__global__ __launch_bounds__(256) void conv_w(const float* __restrict__ mw1,
                                              const float* __restrict__ mw2,
                                              const float* __restrict__ uw1,
                                              const float* __restrict__ uw2,
                                              ushort* __restrict__ w1t,
                                              ushort* __restrict__ w2t,
                                              ushort* __restrict__ uw1t,
                                              ushort* __restrict__ uw2t) {
    int i = blockIdx.x * 256 + threadIdx.x;      // 160*256 = 40960 exact
    if (i < 20480) {
        int h = i / 160, k = i % 160;
        w1t[i] = f2bf(k < 144 ? mw1[k * 128 + h] : 0.0f);
    } else if (i < 28672) {
        int j = i - 20480, o = j / 128, k = j % 128;
        w2t[j] = f2bf(mw2[k * 64 + o]);
    } else if (i < 36864) {
        int j = i - 28672, o = j / 128, k = j % 128;
        uw1t[j] = f2bf(uw1[k * 64 + o]);
    } else {
        int j = i - 36864, o = j / 64, k = j % 64;
        uw2t[j] = f2bf(uw2[k * 64 + o]);
    }
}

// ---- counting sort by dst --------------------------------------------------
__global__ __launch_bounds__(256) void scan1(const int* __restrict__ hist,
                                             int* __restrict__ starts,
                                             int* __restrict__ bsum) {
    __shared__ int s[256];
    int t = threadIdx.x, b = blockIdx.x, i = b * 256 + t;
    int v = (i < NN) ? hist[i] : 0;
    s[t] = v; __syncthreads();
    #pragma unroll
    for (int off = 1; off < 256; off <<= 1) {
        int a = (t >= off) ? s[t - off] : 0;
        __syncthreads();
        s[t] += a;
        __syncthreads();
    }
    if (i < NN) starts[i] = s[t] - v;
    if (t == 255) bsum[b] = s[255];
}

__global__ __launch_bounds__(256) void scan2(int* __restrict__ bsum) {
    __shared__ int s[256];
    int t = threadIdx.x;
    int v = (t < 196) ? bsum[t] : 0;
    s[t] = v; __syncthreads();
    #pragma unroll
    for (int off = 1; off < 256; off <<= 1) {
        int a = (t >= off) ? s[t - off] : 0;
        __syncthreads();
        s[t] += a;
        __syncthreads();
    }
    if (t < 196) bsum[t] = s[t] - v;
}

__global__ __launch_bounds__(256) void scan3(int* __restrict__ starts,
                                             const int* __restrict__ bsum) {
    int i = blockIdx.x * 256 + threadIdx.x;
    if (i < NN) starts[i] += bsum[blockIdx.x];
}

__global__ __launch_bounds__(256) void rank_k(const int* __restrict__ ei,
                                              int* __restrict__ cursor,
                                              int* __restrict__ sortidx) {
    int e = blockIdx.x * 256 + threadIdx.x;      // 800000 exact
    int d = ei[NE + e];
    int pos = atomicAdd(&cursor[d], 1);
    sortidx[pos] = e;
}

// ---------------------------------------------------------------------------
// Edge kernel: sorted edges, MFMA both layers, register-prefetch pipeline
// (issue tile t+1 gathers after sync1 of tile t, commit to LDS after segscan).
// ---------------------------------------------------------------------------
__global__ __launch_bounds__(256, 4) void edge_mfma(
    const ushort* __restrict__ xb,      // [NN][64] bf16
    const int*    __restrict__ sortidx, // [NE]
    const int*    __restrict__ ei,      // [2][NE]
    const float*  __restrict__ elen,    // [NE]
    const ushort* __restrict__ w1t,     // [128][160]
    const float*  __restrict__ mb1,
    const ushort* __restrict__ w2t,     // [64][128]
    const float*  __restrict__ mb2,
    float* __restrict__ agg)            // [NN][64]
{
    __shared__ ushort msg_s[64 * MSW];
    __shared__ ushort h_s[64 * HSW];

    const int tid  = threadIdx.x;
    const int wv   = tid >> 6;
    const int lane = tid & 63;
    const int l16  = lane & 15;
    const int g    = lane >> 4;

    // persistent weight fragments
    short8 a1[2][5];
    #pragma unroll
    for (int m = 0; m < 2; ++m)
        #pragma unroll
        for (int kk = 0; kk < 5; ++kk)
            a1[m][kk] = *(const short8*)(w1t + (wv*32 + m*16 + l16)*160 + kk*32 + g*8);
    short8 a2[4];
    #pragma unroll
    for (int kk = 0; kk < 4; ++kk)
        a2[kk] = *(const short8*)(w2t + (wv*16 + l16)*128 + kk*32 + g*8);
    float b1v[2][4], b2v[4];
    #pragma unroll
    for (int m = 0; m < 2; ++m)
        #pragma unroll
        for (int r = 0; r < 4; ++r)
            b1v[m][r] = mb1[wv*32 + m*16 + g*4 + r];
    #pragma unroll
    for (int r = 0; r < 4; ++r)
        b2v[r] = mb2[wv*16 + g*4 + r];

    // zero K-pad columns 144..159 once (never rewritten)
    {
        int e = tid >> 2, qq = tid & 3;
        *(uint2*)&msg_s[e * MSW + 144 + qq * 4] = make_uint2(0u, 0u);
    }

    const int q  = NT / NBLK, r = NT % NBLK;       // 12, 212
    const int t0 = blockIdx.x < r ? blockIdx.x * (q + 1)
                                  : r * (q + 1) + (blockIdx.x - r) * q;
    const int tn = blockIdx.x < r ? q + 1 : q;

    // ---- prologue: stage tile t0 directly into LDS
    {
        const int e0 = t0 * 64;
        #pragma unroll
        for (int i = 0; i < 4; ++i) {
            int idx = i * 256 + tid, half = idx >> 9, e = (idx >> 3) & 63, c = idx & 7;
            int se = sortidx[e0 + e];
            int n  = ei[half * NE + se];
            *(uint4*)&msg_s[e * MSW + half * 64 + c * 8] =
                *(const uint4*)(xb + (size_t)n * 64 + c * 8);
        }
        #pragma unroll
        for (int i = 0; i < 2; ++i) {
            int idx = i * 256 + tid, e = idx >> 3, p = idx & 7;
            float dist = elen[sortidx[e0 + e]];
            float u0 = dist - (float)(2 * p)     * (10.0f / 15.0f);
            float u1 = dist - (float)(2 * p + 1) * (10.0f / 15.0f);
            uint pk = (uint)f2bf(expf(-u0 * u0 * 4.5f))
                    | ((uint)f2bf(expf(-u1 * u1 * 4.5f)) << 16);
            *(uint*)&msg_s[e * MSW + 128 + p * 2] = pk;
        }
    }
    int dvals[4];
    #pragma unroll
    for (int nt = 0; nt < 4; ++nt)
        dvals[nt] = ei[NE + sortidx[t0 * 64 + nt * 16 + l16]];

    for (int tt = 0; tt < tn; ++tt) {
        __syncthreads();                                    // sync1: staging visible

        // ---- issue next tile's gathers into registers (overlap with MFMA)
        const bool hn = (tt + 1 < tn);
        const int e1 = (t0 + tt + 1) * 64;
        uint4 pf[4]; float pe[2]; int pdv[4];
        if (hn) {
            #pragma unroll
            for (int i = 0; i < 4; ++i) {
                int idx = i * 256 + tid, half = idx >> 9, e = (idx >> 3) & 63, c = idx & 7;
                int se = sortidx[e1 + e];
                int n  = ei[half * NE + se];
                pf[i]  = *(const uint4*)(xb + (size_t)n * 64 + c * 8);
            }
            #pragma unroll
            for (int i = 0; i < 2; ++i) {
                int idx = i * 256 + tid;
                pe[i] = elen[sortidx[e1 + (idx >> 3)]];
            }
            #pragma unroll
            for (int nt = 0; nt < 4; ++nt)
                pdv[nt] = ei[NE + sortidx[e1 + nt * 16 + l16]];
        }

        // ---- layer 1: C1'[hidden][edge]
        f32x4 c1[2][4];
        #pragma unroll
        for (int m = 0; m < 2; ++m)
            #pragma unroll
            for (int nt = 0; nt < 4; ++nt)
                c1[m][nt] = (f32x4){b1v[m][0], b1v[m][1], b1v[m][2], b1v[m][3]};
        #pragma unroll
        for (int nt = 0; nt < 4; ++nt)
            #pragma unroll
            for (int kk = 0; kk < 5; ++kk) {
                short8 b = *(const short8*)&msg_s[(nt*16 + l16)*MSW + kk*32 + g*8];
                c1[0][nt] = __builtin_amdgcn_mfma_f32_16x16x32_bf16(a1[0][kk], b, c1[0][nt], 0, 0, 0);
                c1[1][nt] = __builtin_amdgcn_mfma_f32_16x16x32_bf16(a1[1][kk], b, c1[1][nt], 0, 0, 0);
            }

        // ---- silu -> H[e][h] bf16
        #pragma unroll
        for (int m = 0; m < 2; ++m)
            #pragma unroll
            for (int nt = 0; nt < 4; ++nt) {
                uint2 pk;
                pk.x = (uint)f2bf(silu(c1[m][nt][0])) | ((uint)f2bf(silu(c1[m][nt][1])) << 16);
                pk.y = (uint)f2bf(silu(c1[m][nt][2])) | ((uint)f2bf(silu(c1[m][nt][3])) << 16);
                *(uint2*)&h_s[(nt*16 + l16)*HSW + wv*32 + m*16 + g*4] = pk;
            }
        __syncthreads();                                    // sync2: all msg reads done

        // ---- layer 2: C2'[out][edge]
        f32x4 c2[4];
        #pragma unroll
        for (int nt = 0; nt < 4; ++nt)
            c2[nt] = (f32x4){b2v[0], b2v[1], b2v[2], b2v[3]};
        #pragma unroll
        for (int nt = 0; nt < 4; ++nt)
            #pragma unroll
            for (int kk = 0; kk < 4; ++kk) {
                short8 b = *(const short8*)&h_s[(nt*16 + l16)*HSW + kk*32 + g*8];
                c2[nt] = __builtin_amdgcn_mfma_f32_16x16x32_bf16(a2[kk], b, c2[nt], 0, 0, 0);
            }

        // ---- segmented reduce over equal-dst runs, tail-lane atomics
        #pragma unroll
        for (int nt = 0; nt < 4; ++nt) {
            int d  = dvals[nt];
            int dp = __shfl_up(d, 1, 16);
            int f  = (l16 == 0 || d != dp) ? 1 : 0;
            float v0 = c2[nt][0], v1 = c2[nt][1], v2 = c2[nt][2], v3 = c2[nt][3];
            #pragma unroll
            for (int off = 1; off < 16; off <<= 1) {
                float w0 = __shfl_up(v0, off, 16);
                float w1 = __shfl_up(v1, off, 16);
                float w2 = __shfl_up(v2, off, 16);
                float w3 = __shfl_up(v3, off, 16);
                int   ff = __shfl_up(f,  off, 16);
                if (l16 >= off && !f) { v0 += w0; v1 += w1; v2 += w2; v3 += w3; }
                if (l16 >= off) f |= ff;
            }
            int dn = __shfl_down(d, 1, 16);
            if (l16 == 15 || d != dn) {
                float* p = agg + (size_t)d * 64 + wv * 16 + g * 4;
                atomicAdd(p + 0, v0);
                atomicAdd(p + 1, v1);
                atomicAdd(p + 2, v2);
                atomicAdd(p + 3, v3);
            }
        }

        // ---- commit prefetched tile to LDS (msg reads retired since sync2)
        if (hn) {
            #pragma unroll
            for (int i = 0; i < 4; ++i) {
                int idx = i * 256 + tid, half = idx >> 9, e = (idx >> 3) & 63, c = idx & 7;
                *(uint4*)&msg_s[e * MSW + half * 64 + c * 8] = pf[i];
            }
            #pragma unroll
            for (int i = 0; i < 2; ++i) {
                int idx = i * 256 + tid, e = idx >> 3, p = idx & 7;
                float u0 = pe[i] - (float)(2 * p)     * (10.0f / 15.0f);
                float u1 = pe[i] - (float)(2 * p + 1) * (10.0f / 15.0f);
                uint pk = (uint)f2bf(expf(-u0 * u0 * 4.5f))
                        | ((uint)f2bf(expf(-u1 * u1 * 4.5f)) << 16);
                *(uint*)&msg_s[e * MSW + 128 + p * 2] = pk;
            }
            #pragma unroll
            for (int nt = 0; nt < 4; ++nt) dvals[nt] = pdv[nt];
        }
    }
}

// ---------------------------------------------------------------------------
// Node kernel (MFMA): out = LN(silu([x, agg/cnt] @ uw1 + ub1) @ uw2 + ub2)
// 64-node tiles, transposed layout like edge kernel. 782 blocks (tail guarded).
// ---------------------------------------------------------------------------
__global__ __launch_bounds__(256, 3) void node_mfma(
    const ushort* __restrict__ xb,     // [NN][64] bf16
    const float*  __restrict__ agg,    // [NN][64]
    const int*    __restrict__ hist,   // [NN]
    const ushort* __restrict__ uw1t,   // [64][128]
    const float*  __restrict__ ub1,
    const ushort* __restrict__ uw2t,   // [64][64]
    const float*  __restrict__ ub2,
    const float*  __restrict__ lng,
    const float*  __restrict__ lnb,
    float* __restrict__ out)
{
    __shared__ ushort upd_s[64 * UPS];
    __shared__ ushort hb_s[64 * HBS];
    __shared__ float  out_s[64 * OS];

    const int tid  = threadIdx.x;
    const int wv   = tid >> 6;
    const int lane = tid & 63;
    const int l16  = lane & 15;
    const int g    = lane >> 4;
    const int nb   = blockIdx.x * 64;

    // weight fragments
    short8 au1[4], au2[2];
    #pragma unroll
    for (int kk = 0; kk < 4; ++kk)
        au1[kk] = *(const short8*)(uw1t + (wv*16 + l16)*128 + kk*32 + g*8);
    #pragma unroll
    for (int kk = 0; kk < 2; ++kk)
        au2[kk] = *(const short8*)(uw2t + (wv*16 + l16)*64 + kk*32 + g*8);
    float bu1[4], bu2[4];
    #pragma unroll
    for (int rr = 0; rr < 4; ++rr) {
        bu1[rr] = ub1[wv*16 + g*4 + rr];
        bu2[rr] = ub2[wv*16 + g*4 + rr];
    }

    // ---- stage upd = [x(bf16) | agg/cnt -> bf16]
    #pragma unroll
    for (int i = 0; i < 2; ++i) {
        int idx = i * 256 + tid, nd = idx >> 3, cg = idx & 7;
        int n = nb + nd;
        uint4 v = make_uint4(0u, 0u, 0u, 0u);
        if (n < NN) v = *(const uint4*)(xb + (size_t)n * 64 + cg * 8);
        *(uint4*)&upd_s[nd * UPS + cg * 8] = v;
    }
    {
        int nd = tid >> 2, c16 = (tid & 3) * 16;
        int n = nb + nd;
        float rc = 0.0f;
        if (n < NN) rc = 1.0f / fmaxf((float)hist[n], 1.0f);
        const float4* ap = (const float4*)(agg + (size_t)(n < NN ? n : 0) * 64 + c16);
        #pragma unroll
        for (int j = 0; j < 4; ++j) {
            float4 v = (n < NN) ? ap[j] : make_float4(0.f, 0.f, 0.f, 0.f);
            uint2 pk;
            pk.x = (uint)f2bf(v.x * rc) | ((uint)f2bf(v.y * rc) << 16);
            pk.y = (uint)f2bf(v.z * rc) | ((uint)f2bf(v.w * rc) << 16);
            *(uint2*)&upd_s[nd * UPS + 64 + c16 + j * 4] = pk;
        }
    }
    __syncthreads();

    // ---- layer 1: C1'[h][node], K=128
    f32x4 c1[4];
    #pragma unroll
    for (int nt = 0; nt < 4; ++nt)
        c1[nt] = (f32x4){bu1[0], bu1[1], bu1[2], bu1[3]};
    #pragma unroll
    for (int nt = 0; nt < 4; ++nt)
        #pragma unroll
        for (int kk = 0; kk < 4; ++kk) {
            short8 b = *(const short8*)&upd_s[(nt*16 + l16)*UPS + kk*32 + g*8];
            c1[nt] = __builtin_amdgcn_mfma_f32_16x16x32_bf16(au1[kk], b, c1[nt], 0, 0, 0);
        }
    #pragma unroll
    for (int nt = 0; nt < 4; ++nt) {
        uint2 pk;
        pk.x = (uint)f2bf(silu(c1[nt][0])) | ((uint)f2bf(silu(c1[nt][1])) << 16);
        pk.y = (uint)f2bf(silu(c1[nt][2])) | ((uint)f2bf(silu(c1[nt][3])) << 16);
        *(uint2*)&hb_s[(nt*16 + l16)*HBS + wv*16 + g*4] = pk;
    }
    __syncthreads();

    // ---- layer 2: C2'[o][node], K=64
    f32x4 c2[4];
    #pragma unroll
    for (int nt = 0; nt < 4; ++nt)
        c2[nt] = (f32x4){bu2[0], bu2[1], bu2[2], bu2[3]};
    #pragma unroll
    for (int nt = 0; nt < 4; ++nt)
        #pragma unroll
        for (int kk = 0; kk < 2; ++kk) {
            short8 b = *(const short8*)&hb_s[(nt*16 + l16)*HBS + kk*32 + g*8];
            c2[nt] = __builtin_amdgcn_mfma_f32_16x16x32_bf16(au2[kk], b, c2[nt], 0, 0, 0);
        }
    #pragma unroll
    for (int nt = 0; nt < 4; ++nt)
        *(f32x4*)&out_s[(nt*16 + l16)*OS + wv*16 + g*4] = c2[nt];
    __syncthreads();

    // ---- LayerNorm: wave wv handles nodes wv*16..+15, lane = channel
    float gga = lng[lane], bb = lnb[lane];
    #pragma unroll 4
    for (int i2 = 0; i2 < 16; ++i2) {
        int nd = wv * 16 + i2;
        int n  = nb + nd;
        if (n < NN) {
            float v = out_s[nd * OS + lane];
            float s = v;
            #pragma unroll
            for (int off = 32; off; off >>= 1) s += __shfl_xor(s, off);
            float mu = s * (1.0f / 64.0f);
            float d = v - mu;
            float sq = d * d;
            #pragma unroll
            for (int off = 32; off; off >>= 1) sq += __shfl_xor(sq, off);
            float var = sq * (1.0f / 64.0f);
            out[(size_t)n * 64 + lane] = d * rsqrtf(var + 1e-5f) * gga + bb;
        }
    }
}

extern "C" void kernel_launch(void* const* d_in, const int* in_sizes, int n_in,
                              void* d_out, int out_size, void* d_ws, size_t ws_size,
                              hipStream_t stream) {
    const float* x    = (const float*)d_in[0];
    const int*   ei   = (const int*)  d_in[1];
    const float* elen = (const float*)d_in[3];
    const float* mw1  = (const float*)d_in[4];
    const float* mb1  = (const float*)d_in[5];
    const float* mw2  = (const float*)d_in[6];
    const float* mb2  = (const float*)d_in[7];
    const float* uw1  = (const float*)d_in[8];
    const float* ub1  = (const float*)d_in[9];
    const float* uw2  = (const float*)d_in[10];
    const float* ub2  = (const float*)d_in[11];
    const float* lng  = (const float*)d_in[12];
    const float* lnb  = (const float*)d_in[13];

    // ws layout (bytes):
    // agg 0 | hist 12.8M | starts 13.0M | cursor 13.2M | sortidx 13.4M
    // | xb 16.6M | w1t 23.0M | w2t +40960 | uw1t +16384 | uw2t +16384
    char*  ws      = (char*)d_ws;
    float* agg     = (float*)ws;
    int*   hist    = (int*)(ws + 12800000);
    int*   starts  = (int*)(ws + 13000000);
    int*   cursor  = (int*)(ws + 13200000);
    int*   sortidx = (int*)(ws + 13400000);
    ushort* xb   = (ushort*)(ws + 16600000);
    ushort* w1t  = (ushort*)(ws + 23000000);
    ushort* w2t  = (ushort*)(ws + 23040960);
    ushort* uw1t = (ushort*)(ws + 23057344);
    ushort* uw2t = (ushort*)(ws + 23073728);

    hipMemsetAsync(d_ws, 0, 13000000, stream);              // agg + hist
    conv_x_hist<<<3125, 256, 0, stream>>>(x, ei, xb, hist);
    conv_w<<<160, 256, 0, stream>>>(mw1, mw2, uw1, uw2, w1t, w2t, uw1t, uw2t);
    scan1<<<196, 256, 0, stream>>>(hist, starts, cursor);   // cursor <- block sums
    scan2<<<1, 256, 0, stream>>>(cursor);
    scan3<<<196, 256, 0, stream>>>(starts, cursor);
    hipMemcpyAsync(cursor, starts, 200000, hipMemcpyDeviceToDevice, stream);
    rank_k<<<3125, 256, 0, stream>>>(ei, cursor, sortidx);
    edge_mfma<<<NBLK, 256, 0, stream>>>(xb, sortidx, ei, elen, w1t, mb1, w2t, mb2, agg);
    node_mfma<<<782, 256, 0, stream>>>(xb, agg, hist, uw1t, ub1, uw2t, ub2, lng, lnb,
                                       (float*)d_out);
}

// Round 10
// 453.301 us; speedup vs baseline: 2.5218x; 1.0044x over previous
//
#include <hip/hip_runtime.h>
#include <cstdint>

#define NN 50000
#define NE 800000
#define NT 12500        // edge tiles of 64
#define NBLK 1024       // edge kernel blocks (contiguous tile chunks)
#define MSW 168         // msg LDS row stride, bf16 elems
#define HSW 136         // hidden LDS row stride
#define UPS 136         // node upd LDS stride (bf16)
#define HBS 72          // node hidden LDS stride (bf16)
#define OS  68          // node out LDS stride (f32)

typedef short short8 __attribute__((ext_vector_type(8)));
typedef float f32x4  __attribute__((ext_vector_type(4)));

__device__ __forceinline__ ushort f2bf(float f) {
    union { float f; uint u; } v; v.f = f;
    return (ushort)((v.u + 0x7FFFu + ((v.u >> 16) & 1u)) >> 16);   // RNE
}
__device__ __forceinline__ float silu(float v) {
    return __fdividef(v, 1.0f + __expf(-v));
}

// ---- prep: x -> bf16, fused with XCD-local dst histogram -------------------
__global__ __launch_bounds__(256) void conv_x_hist(const float* __restrict__ x,
                                                   const int* __restrict__ ei,
                                                   ushort* __restrict__ xb,
                                                   int* __restrict__ h2) {
    int i = blockIdx.x * 256 + threadIdx.x;      // 800000 exact
    float4 v = ((const float4*)x)[i];
    uint2 o;
    o.x = (uint)f2bf(v.x) | ((uint)f2bf(v.y) << 16);
    o.y = (uint)f2bf(v.z) | ((uint)f2bf(v.w) << 16);
    ((uint2*)xb)[i] = o;
    atomicAdd(&h2[(blockIdx.x & 7) * NN + ei[NE + i]], 1);
}

// ---- prep: all four weights -> bf16 transposed -----------------------------
__global__ __launch_bounds__(256) void conv_w(const float* __restrict__ mw1,
                                              const float* __restrict__ mw2,
                                              const float* __restrict__ uw1,
                                              const float* __restrict__ uw2,
                                              ushort* __restrict__ w1t,
                                              ushort* __restrict__ w2t,
                                              ushort* __restrict__ uw1t,
                                              ushort* __restrict__ uw2t) {
    int i = blockIdx.x * 256 + threadIdx.x;      // 160*256 = 40960 exact
    if (i < 20480) {
        int h = i / 160, k = i % 160;
        w1t[i] = f2bf(k < 144 ? mw1[k * 128 + h] : 0.0f);
    } else if (i < 28672) {
        int j = i - 20480, o = j / 128, k = j % 128;
        w2t[j] = f2bf(mw2[k * 64 + o]);
    } else if (i < 36864) {
        int j = i - 28672, o = j / 128, k = j % 128;
        uw1t[j] = f2bf(uw1[k * 64 + o]);
    } else {
        int j = i - 36864, o = j / 64, k = j % 64;
        uw2t[j] = f2bf(uw2[k * 64 + o]);
    }
}

// ---- counting sort by dst (XCD-partitioned) --------------------------------
__global__ __launch_bounds__(256) void scan1(const int* __restrict__ h2,
                                             int* __restrict__ hist_comb,
                                             int* __restrict__ starts,
                                             int* __restrict__ bsum) {
    __shared__ int s[256];
    int t = threadIdx.x, b = blockIdx.x, i = b * 256 + t;
    int v = 0;
    if (i < NN) {
        #pragma unroll
        for (int xg = 0; xg < 8; ++xg) v += h2[xg * NN + i];
        hist_comb[i] = v;
    }
    s[t] = v; __syncthreads();
    #pragma unroll
    for (int off = 1; off < 256; off <<= 1) {
        int a = (t >= off) ? s[t - off] : 0;
        __syncthreads();
        s[t] += a;
        __syncthreads();
    }
    if (i < NN) starts[i] = s[t] - v;
    if (t == 255) bsum[b] = s[255];
}

__global__ __launch_bounds__(256) void scan2(int* __restrict__ bsum) {
    __shared__ int s[256];
    int t = threadIdx.x;
    int v = (t < 196) ? bsum[t] : 0;
    s[t] = v; __syncthreads();
    #pragma unroll
    for (int off = 1; off < 256; off <<= 1) {
        int a = (t >= off) ? s[t - off] : 0;
        __syncthreads();
        s[t] += a;
        __syncthreads();
    }
    if (t < 196) bsum[t] = s[t] - v;
}

__global__ __launch_bounds__(256) void scan3(int* __restrict__ starts,
                                             const int* __restrict__ bsum) {
    int i = blockIdx.x * 256 + threadIdx.x;
    if (i < NN) starts[i] += bsum[blockIdx.x];
}

// per-(bin,xcd) output window base: starts[d] + prefix of h2[x'<x][d]
__global__ __launch_bounds__(256) void cursor_init(const int* __restrict__ starts,
                                                   const int* __restrict__ h2,
                                                   int* __restrict__ cursor2) {
    int d = blockIdx.x * 256 + threadIdx.x;
    int xg = blockIdx.y;
    if (d < NN) {
        int c = starts[d];
        for (int xp = 0; xp < xg; ++xp) c += h2[xp * NN + d];
        cursor2[xg * NN + d] = c;
    }
}

__global__ __launch_bounds__(256) void rank_k(const int* __restrict__ ei,
                                              int* __restrict__ cursor2,
                                              int* __restrict__ sortidx) {
    int e = blockIdx.x * 256 + threadIdx.x;      // 800000 exact
    int d = ei[NE + e];
    int pos = atomicAdd(&cursor2[(blockIdx.x & 7) * NN + d], 1);
    sortidx[pos] = e;
}

// ---------------------------------------------------------------------------
// Edge kernel: sorted edges, MFMA both layers, register-prefetch pipeline.
// ---------------------------------------------------------------------------
__global__ __launch_bounds__(256, 4) void edge_mfma(
    const ushort* __restrict__ xb,      // [NN][64] bf16
    const int*    __restrict__ sortidx, // [NE]
    const int*    __restrict__ ei,      // [2][NE]
    const float*  __restrict__ elen,    // [NE]
    const ushort* __restrict__ w1t,     // [128][160]
    const float*  __restrict__ mb1,
    const ushort* __restrict__ w2t,     // [64][128]
    const float*  __restrict__ mb2,
    float* __restrict__ agg)            // [NN][64]
{
    __shared__ ushort msg_s[64 * MSW];
    __shared__ ushort h_s[64 * HSW];

    const int tid  = threadIdx.x;
    const int wv   = tid >> 6;
    const int lane = tid & 63;
    const int l16  = lane & 15;
    const int g    = lane >> 4;

    // persistent weight fragments
    short8 a1[2][5];
    #pragma unroll
    for (int m = 0; m < 2; ++m)
        #pragma unroll
        for (int kk = 0; kk < 5; ++kk)
            a1[m][kk] = *(const short8*)(w1t + (wv*32 + m*16 + l16)*160 + kk*32 + g*8);
    short8 a2[4];
    #pragma unroll
    for (int kk = 0; kk < 4; ++kk)
        a2[kk] = *(const short8*)(w2t + (wv*16 + l16)*128 + kk*32 + g*8);
    float b1v[2][4], b2v[4];
    #pragma unroll
    for (int m = 0; m < 2; ++m)
        #pragma unroll
        for (int r = 0; r < 4; ++r)
            b1v[m][r] = mb1[wv*32 + m*16 + g*4 + r];
    #pragma unroll
    for (int r = 0; r < 4; ++r)
        b2v[r] = mb2[wv*16 + g*4 + r];

    // zero K-pad columns 144..159 once (never rewritten)
    {
        int e = tid >> 2, qq = tid & 3;
        *(uint2*)&msg_s[e * MSW + 144 + qq * 4] = make_uint2(0u, 0u);
    }

    const int q  = NT / NBLK, r = NT % NBLK;       // 12, 212
    const int t0 = blockIdx.x < r ? blockIdx.x * (q + 1)
                                  : r * (q + 1) + (blockIdx.x - r) * q;
    const int tn = blockIdx.x < r ? q + 1 : q;

    // ---- prologue: stage tile t0 directly into LDS
    {
        const int e0 = t0 * 64;
        #pragma unroll
        for (int i = 0; i < 4; ++i) {
            int idx = i * 256 + tid, half = idx >> 9, e = (idx >> 3) & 63, c = idx & 7;
            int se = sortidx[e0 + e];
            int n  = ei[half * NE + se];
            *(uint4*)&msg_s[e * MSW + half * 64 + c * 8] =
                *(const uint4*)(xb + (size_t)n * 64 + c * 8);
        }
        #pragma unroll
        for (int i = 0; i < 2; ++i) {
            int idx = i * 256 + tid, e = idx >> 3, p = idx & 7;
            float dist = elen[sortidx[e0 + e]];
            float u0 = dist - (float)(2 * p)     * (10.0f / 15.0f);
            float u1 = dist - (float)(2 * p + 1) * (10.0f / 15.0f);
            uint pk = (uint)f2bf(__expf(-u0 * u0 * 4.5f))
                    | ((uint)f2bf(__expf(-u1 * u1 * 4.5f)) << 16);
            *(uint*)&msg_s[e * MSW + 128 + p * 2] = pk;
        }
    }
    int dvals[4];
    #pragma unroll
    for (int nt = 0; nt < 4; ++nt)
        dvals[nt] = ei[NE + sortidx[t0 * 64 + nt * 16 + l16]];

    for (int tt = 0; tt < tn; ++tt) {
        __syncthreads();                                    // sync1: staging visible

        // ---- issue next tile's gathers into registers (overlap with MFMA)
        const bool hn = (tt + 1 < tn);
        const int e1 = (t0 + tt + 1) * 64;
        uint4 pf[4]; float pe[2]; int pdv[4];
        if (hn) {
            #pragma unroll
            for (int i = 0; i < 4; ++i) {
                int idx = i * 256 + tid, half = idx >> 9, e = (idx >> 3) & 63, c = idx & 7;
                int se = sortidx[e1 + e];
                int n  = ei[half * NE + se];
                pf[i]  = *(const uint4*)(xb + (size_t)n * 64 + c * 8);
            }
            #pragma unroll
            for (int i = 0; i < 2; ++i) {
                int idx = i * 256 + tid;
                pe[i] = elen[sortidx[e1 + (idx >> 3)]];
            }
            #pragma unroll
            for (int nt = 0; nt < 4; ++nt)
                pdv[nt] = ei[NE + sortidx[e1 + nt * 16 + l16]];
        }

        // ---- layer 1: C1'[hidden][edge]
        f32x4 c1[2][4];
        #pragma unroll
        for (int m = 0; m < 2; ++m)
            #pragma unroll
            for (int nt = 0; nt < 4; ++nt)
                c1[m][nt] = (f32x4){b1v[m][0], b1v[m][1], b1v[m][2], b1v[m][3]};
        #pragma unroll
        for (int nt = 0; nt < 4; ++nt)
            #pragma unroll
            for (int kk = 0; kk < 5; ++kk) {
                short8 b = *(const short8*)&msg_s[(nt*16 + l16)*MSW + kk*32 + g*8];
                c1[0][nt] = __builtin_amdgcn_mfma_f32_16x16x32_bf16(a1[0][kk], b, c1[0][nt], 0, 0, 0);
                c1[1][nt] = __builtin_amdgcn_mfma_f32_16x16x32_bf16(a1[1][kk], b, c1[1][nt], 0, 0, 0);
            }

        // ---- silu -> H[e][h] bf16
        #pragma unroll
        for (int m = 0; m < 2; ++m)
            #pragma unroll
            for (int nt = 0; nt < 4; ++nt) {
                uint2 pk;
                pk.x = (uint)f2bf(silu(c1[m][nt][0])) | ((uint)f2bf(silu(c1[m][nt][1])) << 16);
                pk.y = (uint)f2bf(silu(c1[m][nt][2])) | ((uint)f2bf(silu(c1[m][nt][3])) << 16);
                *(uint2*)&h_s[(nt*16 + l16)*HSW + wv*32 + m*16 + g*4] = pk;
            }
        __syncthreads();                                    // sync2: all msg reads done

        // ---- layer 2: C2'[out][edge]
        f32x4 c2[4];
        #pragma unroll
        for (int nt = 0; nt < 4; ++nt)
            c2[nt] = (f32x4){b2v[0], b2v[1], b2v[2], b2v[3]};
        #pragma unroll
        for (int nt = 0; nt < 4; ++nt)
            #pragma unroll
            for (int kk = 0; kk < 4; ++kk) {
                short8 b = *(const short8*)&h_s[(nt*16 + l16)*HSW + kk*32 + g*8];
                c2[nt] = __builtin_amdgcn_mfma_f32_16x16x32_bf16(a2[kk], b, c2[nt], 0, 0, 0);
            }

        // ---- segmented reduce over equal-dst runs, tail-lane atomics
        #pragma unroll
        for (int nt = 0; nt < 4; ++nt) {
            int d  = dvals[nt];
            int dp = __shfl_up(d, 1, 16);
            int f  = (l16 == 0 || d != dp) ? 1 : 0;
            float v0 = c2[nt][0], v1 = c2[nt][1], v2 = c2[nt][2], v3 = c2[nt][3];
            #pragma unroll
            for (int off = 1; off < 16; off <<= 1) {
                float w0 = __shfl_up(v0, off, 16);
                float w1 = __shfl_up(v1, off, 16);
                float w2 = __shfl_up(v2, off, 16);
                float w3 = __shfl_up(v3, off, 16);
                int   ff = __shfl_up(f,  off, 16);
                if (l16 >= off && !f) { v0 += w0; v1 += w1; v2 += w2; v3 += w3; }
                if (l16 >= off) f |= ff;
            }
            int dn = __shfl_down(d, 1, 16);
            if (l16 == 15 || d != dn) {
                float* p = agg + (size_t)d * 64 + wv * 16 + g * 4;
                atomicAdd(p + 0, v0);
                atomicAdd(p + 1, v1);
                atomicAdd(p + 2, v2);
                atomicAdd(p + 3, v3);
            }
        }

        // ---- commit prefetched tile to LDS (msg reads retired since sync2)
        if (hn) {
            #pragma unroll
            for (int i = 0; i < 4; ++i) {
                int idx = i * 256 + tid, half = idx >> 9, e = (idx >> 3) & 63, c = idx & 7;
                *(uint4*)&msg_s[e * MSW + half * 64 + c * 8] = pf[i];
            }
            #pragma unroll
            for (int i = 0; i < 2; ++i) {
                int idx = i * 256 + tid, e = idx >> 3, p = idx & 7;
                float u0 = pe[i] - (float)(2 * p)     * (10.0f / 15.0f);
                float u1 = pe[i] - (float)(2 * p + 1) * (10.0f / 15.0f);
                uint pk = (uint)f2bf(__expf(-u0 * u0 * 4.5f))
                        | ((uint)f2bf(__expf(-u1 * u1 * 4.5f)) << 16);
                *(uint*)&msg_s[e * MSW + 128 + p * 2] = pk;
            }
            #pragma unroll
            for (int nt = 0; nt < 4; ++nt) dvals[nt] = pdv[nt];
        }
    }
}

// ---------------------------------------------------------------------------
// Node kernel (MFMA): out = LN(silu([x, agg/cnt] @ uw1 + ub1) @ uw2 + ub2)
// ---------------------------------------------------------------------------
__global__ __launch_bounds__(256, 3) void node_mfma(
    const ushort* __restrict__ xb,     // [NN][64] bf16
    const float*  __restrict__ agg,    // [NN][64]
    const int*    __restrict__ hist,   // [NN] combined
    const ushort* __restrict__ uw1t,   // [64][128]
    const float*  __restrict__ ub1,
    const ushort* __restrict__ uw2t,   // [64][64]
    const float*  __restrict__ ub2,
    const float*  __restrict__ lng,
    const float*  __restrict__ lnb,
    float* __restrict__ out)
{
    __shared__ ushort upd_s[64 * UPS];
    __shared__ ushort hb_s[64 * HBS];
    __shared__ float  out_s[64 * OS];

    const int tid  = threadIdx.x;
    const int wv   = tid >> 6;
    const int lane = tid & 63;
    const int l16  = lane & 15;
    const int g    = lane >> 4;
    const int nb   = blockIdx.x * 64;

    // weight fragments
    short8 au1[4], au2[2];
    #pragma unroll
    for (int kk = 0; kk < 4; ++kk)
        au1[kk] = *(const short8*)(uw1t + (wv*16 + l16)*128 + kk*32 + g*8);
    #pragma unroll
    for (int kk = 0; kk < 2; ++kk)
        au2[kk] = *(const short8*)(uw2t + (wv*16 + l16)*64 + kk*32 + g*8);
    float bu1[4], bu2[4];
    #pragma unroll
    for (int rr = 0; rr < 4; ++rr) {
        bu1[rr] = ub1[wv*16 + g*4 + rr];
        bu2[rr] = ub2[wv*16 + g*4 + rr];
    }

    // ---- stage upd = [x(bf16) | agg/cnt -> bf16]
    #pragma unroll
    for (int i = 0; i < 2; ++i) {
        int idx = i * 256 + tid, nd = idx >> 3, cg = idx & 7;
        int n = nb + nd;
        uint4 v = make_uint4(0u, 0u, 0u, 0u);
        if (n < NN) v = *(const uint4*)(xb + (size_t)n * 64 + cg * 8);
        *(uint4*)&upd_s[nd * UPS + cg * 8] = v;
    }
    {
        int nd = tid >> 2, c16 = (tid & 3) * 16;
        int n = nb + nd;
        float rc = 0.0f;
        if (n < NN) rc = 1.0f / fmaxf((float)hist[n], 1.0f);
        const float4* ap = (const float4*)(agg + (size_t)(n < NN ? n : 0) * 64 + c16);
        #pragma unroll
        for (int j = 0; j < 4; ++j) {
            float4 v = (n < NN) ? ap[j] : make_float4(0.f, 0.f, 0.f, 0.f);
            uint2 pk;
            pk.x = (uint)f2bf(v.x * rc) | ((uint)f2bf(v.y * rc) << 16);
            pk.y = (uint)f2bf(v.z * rc) | ((uint)f2bf(v.w * rc) << 16);
            *(uint2*)&upd_s[nd * UPS + 64 + c16 + j * 4] = pk;
        }
    }
    __syncthreads();

    // ---- layer 1: C1'[h][node], K=128
    f32x4 c1[4];
    #pragma unroll
    for (int nt = 0; nt < 4; ++nt)
        c1[nt] = (f32x4){bu1[0], bu1[1], bu1[2], bu1[3]};
    #pragma unroll
    for (int nt = 0; nt < 4; ++nt)
        #pragma unroll
        for (int kk = 0; kk < 4; ++kk) {
            short8 b = *(const short8*)&upd_s[(nt*16 + l16)*UPS + kk*32 + g*8];
            c1[nt] = __builtin_amdgcn_mfma_f32_16x16x32_bf16(au1[kk], b, c1[nt], 0, 0, 0);
        }
    #pragma unroll
    for (int nt = 0; nt < 4; ++nt) {
        uint2 pk;
        pk.x = (uint)f2bf(silu(c1[nt][0])) | ((uint)f2bf(silu(c1[nt][1])) << 16);
        pk.y = (uint)f2bf(silu(c1[nt][2])) | ((uint)f2bf(silu(c1[nt][3])) << 16);
        *(uint2*)&hb_s[(nt*16 + l16)*HBS + wv*16 + g*4] = pk;
    }
    __syncthreads();

    // ---- layer 2: C2'[o][node], K=64
    f32x4 c2[4];
    #pragma unroll
    for (int nt = 0; nt < 4; ++nt)
        c2[nt] = (f32x4){bu2[0], bu2[1], bu2[2], bu2[3]};
    #pragma unroll
    for (int nt = 0; nt < 4; ++nt)
        #pragma unroll
        for (int kk = 0; kk < 2; ++kk) {
            short8 b = *(const short8*)&hb_s[(nt*16 + l16)*HBS + kk*32 + g*8];
            c2[nt] = __builtin_amdgcn_mfma_f32_16x16x32_bf16(au2[kk], b, c2[nt], 0, 0, 0);
        }
    #pragma unroll
    for (int nt = 0; nt < 4; ++nt)
        *(f32x4*)&out_s[(nt*16 + l16)*OS + wv*16 + g*4] = c2[nt];
    __syncthreads();

    // ---- LayerNorm: wave wv handles nodes wv*16..+15, lane = channel
    float gga = lng[lane], bb = lnb[lane];
    #pragma unroll 4
    for (int i2 = 0; i2 < 16; ++i2) {
        int nd = wv * 16 + i2;
        int n  = nb + nd;
        if (n < NN) {
            float v = out_s[nd * OS + lane];
            float s = v;
            #pragma unroll
            for (int off = 32; off; off >>= 1) s += __shfl_xor(s, off);
            float mu = s * (1.0f / 64.0f);
            float d = v - mu;
            float sq = d * d;
            #pragma unroll
            for (int off = 32; off; off >>= 1) sq += __shfl_xor(sq, off);
            float var = sq * (1.0f / 64.0f);
            out[(size_t)n * 64 + lane] = d * rsqrtf(var + 1e-5f) * gga + bb;
        }
    }
}

extern "C" void kernel_launch(void* const* d_in, const int* in_sizes, int n_in,
                              void* d_out, int out_size, void* d_ws, size_t ws_size,
                              hipStream_t stream) {
    const float* x    = (const float*)d_in[0];
    const int*   ei   = (const int*)  d_in[1];
    const float* elen = (const float*)d_in[3];
    const float* mw1  = (const float*)d_in[4];
    const float* mb1  = (const float*)d_in[5];
    const float* mw2  = (const float*)d_in[6];
    const float* mb2  = (const float*)d_in[7];
    const float* uw1  = (const float*)d_in[8];
    const float* ub1  = (const float*)d_in[9];
    const float* uw2  = (const float*)d_in[10];
    const float* ub2  = (const float*)d_in[11];
    const float* lng  = (const float*)d_in[12];
    const float* lnb  = (const float*)d_in[13];

    // ws layout (bytes). Region A [0,12.8M) holds prep buffers, then is
    // re-zeroed to become agg before edge_mfma (prep buffers dead by then):
    //   h2      0        .. 1,600,000   (8 x 50000 ints, [xcd][bin])
    //   starts  1,600,000.. 1,800,000
    //   bsum    1,800,000.. 1,801,024
    //   cursor2 1,900,000.. 3,500,000   (8 x 50000 ints)
    // agg       0        .. 12,800,000  (after 2nd memset)
    // hist_comb 12,800,000..13,000,000
    // sortidx   13,000,000..16,200,000
    // xb        16,200,000..22,600,000
    // weights   22,600,000..22,690,112
    char*  ws        = (char*)d_ws;
    float* agg       = (float*)ws;
    int*   h2        = (int*)(ws + 0);
    int*   starts    = (int*)(ws + 1600000);
    int*   bsum      = (int*)(ws + 1800000);
    int*   cursor2   = (int*)(ws + 1900000);
    int*   hist_comb = (int*)(ws + 12800000);
    int*   sortidx   = (int*)(ws + 13000000);
    ushort* xb   = (ushort*)(ws + 16200000);
    ushort* w1t  = (ushort*)(ws + 22600000);
    ushort* w2t  = (ushort*)(ws + 22640960);
    ushort* uw1t = (ushort*)(ws + 22657344);
    ushort* uw2t = (ushort*)(ws + 22673728);

    hipMemsetAsync(h2, 0, 1600000, stream);                 // sub-histograms
    conv_x_hist<<<3125, 256, 0, stream>>>(x, ei, xb, h2);
    conv_w<<<160, 256, 0, stream>>>(mw1, mw2, uw1, uw2, w1t, w2t, uw1t, uw2t);
    scan1<<<196, 256, 0, stream>>>(h2, hist_comb, starts, bsum);
    scan2<<<1, 256, 0, stream>>>(bsum);
    scan3<<<196, 256, 0, stream>>>(starts, bsum);
    cursor_init<<<dim3(196, 8), 256, 0, stream>>>(starts, h2, cursor2);
    rank_k<<<3125, 256, 0, stream>>>(ei, cursor2, sortidx);
    hipMemsetAsync(agg, 0, 12800000, stream);               // agg (prep dead now)
    edge_mfma<<<NBLK, 256, 0, stream>>>(xb, sortidx, ei, elen, w1t, mb1, w2t, mb2, agg);
    node_mfma<<<782, 256, 0, stream>>>(xb, agg, hist_comb, uw1t, ub1, uw2t, ub2,
                                       lng, lnb, (float*)d_out);
}

// Round 12
// 363.256 us; speedup vs baseline: 3.1469x; 1.2479x over previous
//
#include <hip/hip_runtime.h>
#include <cstdint>

#define NN 50000
#define NE 800000
#define NT 12500        // edge tiles of 64
#define NBLK 1792       // edge kernel blocks (contiguous tile chunks, 7/CU target)
#define MSW 168         // msg LDS row stride, bf16 elems (336B: 2-way banks, free)
#define HSW 136         // hidden stride, overlaid into msg buffer (272B, 2-way free)
#define UPS 136         // node upd LDS stride (bf16)
#define HBS 72          // node hidden LDS stride (bf16)

typedef short short8 __attribute__((ext_vector_type(8)));
typedef float f32x4  __attribute__((ext_vector_type(4)));

__device__ __forceinline__ ushort f2bf(float f) {
    union { float f; uint u; } v; v.f = f;
    return (ushort)((v.u + 0x7FFFu + ((v.u >> 16) & 1u)) >> 16);   // RNE
}
__device__ __forceinline__ float silu(float v) {
    return __fdividef(v, 1.0f + __expf(-v));
}

// ---- prep: x -> bf16, fused with XCD-local dst histogram -------------------
__global__ __launch_bounds__(256) void conv_x_hist(const float* __restrict__ x,
                                                   const int* __restrict__ ei,
                                                   ushort* __restrict__ xb,
                                                   int* __restrict__ h2) {
    int i = blockIdx.x * 256 + threadIdx.x;      // 800000 exact
    float4 v = ((const float4*)x)[i];
    uint2 o;
    o.x = (uint)f2bf(v.x) | ((uint)f2bf(v.y) << 16);
    o.y = (uint)f2bf(v.z) | ((uint)f2bf(v.w) << 16);
    ((uint2*)xb)[i] = o;
    atomicAdd(&h2[(blockIdx.x & 7) * NN + ei[NE + i]], 1);
}

// ---- prep: all four weights -> bf16 transposed -----------------------------
__global__ __launch_bounds__(256) void conv_w(const float* __restrict__ mw1,
                                              const float* __restrict__ mw2,
                                              const float* __restrict__ uw1,
                                              const float* __restrict__ uw2,
                                              ushort* __restrict__ w1t,
                                              ushort* __restrict__ w2t,
                                              ushort* __restrict__ uw1t,
                                              ushort* __restrict__ uw2t) {
    int i = blockIdx.x * 256 + threadIdx.x;      // 160*256 = 40960 exact
    if (i < 20480) {
        int h = i / 160, k = i % 160;
        w1t[i] = f2bf(k < 144 ? mw1[k * 128 + h] : 0.0f);
    } else if (i < 28672) {
        int j = i - 20480, o = j / 128, k = j % 128;
        w2t[j] = f2bf(mw2[k * 64 + o]);
    } else if (i < 36864) {
        int j = i - 28672, o = j / 128, k = j % 128;
        uw1t[j] = f2bf(uw1[k * 64 + o]);
    } else {
        int j = i - 36864, o = j / 64, k = j % 64;
        uw2t[j] = f2bf(uw2[k * 64 + o]);
    }
}

// ---- counting sort by dst (XCD-partitioned) --------------------------------
__global__ __launch_bounds__(256) void scan1(const int* __restrict__ h2,
                                             int* __restrict__ hist_comb,
                                             int* __restrict__ starts,
                                             int* __restrict__ bsum) {
    __shared__ int s[256];
    int t = threadIdx.x, b = blockIdx.x, i = b * 256 + t;
    int v = 0;
    if (i < NN) {
        #pragma unroll
        for (int xg = 0; xg < 8; ++xg) v += h2[xg * NN + i];
        hist_comb[i] = v;
    }
    s[t] = v; __syncthreads();
    #pragma unroll
    for (int off = 1; off < 256; off <<= 1) {
        int a = (t >= off) ? s[t - off] : 0;
        __syncthreads();
        s[t] += a;
        __syncthreads();
    }
    if (i < NN) starts[i] = s[t] - v;            // block-local exclusive
    if (t == 255) bsum[b] = s[255];
}

__global__ __launch_bounds__(256) void scan2(int* __restrict__ bsum) {
    __shared__ int s[256];
    int t = threadIdx.x;
    int v = (t < 196) ? bsum[t] : 0;
    s[t] = v; __syncthreads();
    #pragma unroll
    for (int off = 1; off < 256; off <<= 1) {
        int a = (t >= off) ? s[t - off] : 0;
        __syncthreads();
        s[t] += a;
        __syncthreads();
    }
    if (t < 196) bsum[t] = s[t] - v;             // exclusive, in place
}

// per-(bin,xcd) window base = global start + running prefix over xcd groups
__global__ __launch_bounds__(256) void cursor_init(const int* __restrict__ starts,
                                                   const int* __restrict__ bsum,
                                                   const int* __restrict__ h2,
                                                   int* __restrict__ cursor2) {
    int d = blockIdx.x * 256 + threadIdx.x;
    if (d < NN) {
        int c = starts[d] + bsum[blockIdx.x];
        #pragma unroll
        for (int xg = 0; xg < 8; ++xg) {
            cursor2[xg * NN + d] = c;
            c += h2[xg * NN + d];
        }
    }
}

// emits SORTED edge data directly: ssdp = src | dst<<16 (ids < 65536), selen
__global__ __launch_bounds__(256) void rank_k(const int* __restrict__ ei,
                                              const float* __restrict__ elen,
                                              int* __restrict__ cursor2,
                                              uint* __restrict__ ssdp,
                                              float* __restrict__ selen) {
    int e = blockIdx.x * 256 + threadIdx.x;      // 800000 exact
    int sN = ei[e];
    int d  = ei[NE + e];
    float L = elen[e];
    int pos = atomicAdd(&cursor2[(blockIdx.x & 7) * NN + d], 1);
    ssdp[pos]  = (uint)sN | ((uint)d << 16);
    selen[pos] = L;
}

// ---------------------------------------------------------------------------
// Edge kernel: sorted edges, single-level gather, LDS overlay (msg/hidden
// share one buffer; 4 barriers/tile), register prefetch of next tile.
// ---------------------------------------------------------------------------
__global__ __launch_bounds__(256, 4) void edge_mfma(
    const ushort* __restrict__ xb,     // [NN][64] bf16
    const uint*   __restrict__ ssdp,   // [NE] src|dst<<16, sorted by dst
    const float*  __restrict__ selen,  // [NE] sorted
    const ushort* __restrict__ w1t,    // [128][160]
    const float*  __restrict__ mb1,
    const ushort* __restrict__ w2t,    // [64][128]
    const float*  __restrict__ mb2,
    float* __restrict__ agg)           // [NN][64]
{
    __shared__ ushort buf[64 * MSW];   // 21504 B: msg tile, then hidden overlay

    const int tid  = threadIdx.x;
    const int wv   = tid >> 6;
    const int lane = tid & 63;
    const int l16  = lane & 15;
    const int g    = lane >> 4;

    // persistent weight fragments
    short8 a1[2][5];
    #pragma unroll
    for (int m = 0; m < 2; ++m)
        #pragma unroll
        for (int kk = 0; kk < 5; ++kk)
            a1[m][kk] = *(const short8*)(w1t + (wv*32 + m*16 + l16)*160 + kk*32 + g*8);
    short8 a2[4];
    #pragma unroll
    for (int kk = 0; kk < 4; ++kk)
        a2[kk] = *(const short8*)(w2t + (wv*16 + l16)*128 + kk*32 + g*8);
    float b1v[2][4], b2v[4];
    #pragma unroll
    for (int m = 0; m < 2; ++m)
        #pragma unroll
        for (int r = 0; r < 4; ++r)
            b1v[m][r] = mb1[wv*32 + m*16 + g*4 + r];
    #pragma unroll
    for (int r = 0; r < 4; ++r)
        b2v[r] = mb2[wv*16 + g*4 + r];

    const int q  = NT / NBLK, r = NT % NBLK;       // 6, 1748
    const int t0 = blockIdx.x < r ? blockIdx.x * (q + 1)
                                  : r * (q + 1) + (blockIdx.x - r) * q;
    const int tn = blockIdx.x < r ? q + 1 : q;

    const int ea = tid >> 3, cc = tid & 7;

    // ---- prologue: stage tile t0 directly into LDS
    {
        const int e0 = t0 * 64;
        uint sda = ssdp[e0 + ea], sdb = ssdp[e0 + 32 + ea];
        float ela = selen[e0 + ea], elb = selen[e0 + 32 + ea];
        *(uint4*)&buf[ ea       *MSW      + cc*8] = *(const uint4*)(xb + (size_t)(sda & 0xFFFFu)*64 + cc*8);
        *(uint4*)&buf[(32 + ea) *MSW      + cc*8] = *(const uint4*)(xb + (size_t)(sdb & 0xFFFFu)*64 + cc*8);
        *(uint4*)&buf[ ea       *MSW + 64 + cc*8] = *(const uint4*)(xb + (size_t)(sda >> 16)*64 + cc*8);
        *(uint4*)&buf[(32 + ea) *MSW + 64 + cc*8] = *(const uint4*)(xb + (size_t)(sdb >> 16)*64 + cc*8);
        float u0 = ela - (float)(2*cc)   * (10.0f/15.0f);
        float u1 = ela - (float)(2*cc+1) * (10.0f/15.0f);
        *(uint*)&buf[ea*MSW + 128 + cc*2] =
            (uint)f2bf(__expf(-u0*u0*4.5f)) | ((uint)f2bf(__expf(-u1*u1*4.5f)) << 16);
        float v0 = elb - (float)(2*cc)   * (10.0f/15.0f);
        float v1 = elb - (float)(2*cc+1) * (10.0f/15.0f);
        *(uint*)&buf[(32+ea)*MSW + 128 + cc*2] =
            (uint)f2bf(__expf(-v0*v0*4.5f)) | ((uint)f2bf(__expf(-v1*v1*4.5f)) << 16);
        int ez = tid >> 2, qq = tid & 3;
        *(uint2*)&buf[ez*MSW + 144 + qq*4] = make_uint2(0u, 0u);
    }
    int dvals[4];
    #pragma unroll
    for (int nt = 0; nt < 4; ++nt)
        dvals[nt] = (int)(ssdp[t0*64 + nt*16 + l16] >> 16);

    for (int tt = 0; tt < tn; ++tt) {
        __syncthreads();                               // S1: staging visible

        // ---- prefetch next tile into registers
        const bool hn = (tt + 1 < tn);
        const int e1 = (t0 + tt + 1) * 64;
        uint4 pf0, pf1, pf2, pf3; float pea = 0.f, peb = 0.f; int pdv[4];
        if (hn) {
            uint sda = ssdp[e1 + ea], sdb = ssdp[e1 + 32 + ea];
            pea = selen[e1 + ea]; peb = selen[e1 + 32 + ea];
            pf0 = *(const uint4*)(xb + (size_t)(sda & 0xFFFFu)*64 + cc*8);
            pf1 = *(const uint4*)(xb + (size_t)(sdb & 0xFFFFu)*64 + cc*8);
            pf2 = *(const uint4*)(xb + (size_t)(sda >> 16)*64 + cc*8);
            pf3 = *(const uint4*)(xb + (size_t)(sdb >> 16)*64 + cc*8);
            #pragma unroll
            for (int nt = 0; nt < 4; ++nt)
                pdv[nt] = (int)(ssdp[e1 + nt*16 + l16] >> 16);
        }

        // ---- layer 1: C1'[hidden][edge], K=160
        f32x4 c1[2][4];
        #pragma unroll
        for (int m = 0; m < 2; ++m)
            #pragma unroll
            for (int nt = 0; nt < 4; ++nt)
                c1[m][nt] = (f32x4){b1v[m][0], b1v[m][1], b1v[m][2], b1v[m][3]};
        #pragma unroll
        for (int nt = 0; nt < 4; ++nt)
            #pragma unroll
            for (int kk = 0; kk < 5; ++kk) {
                short8 b = *(const short8*)&buf[(nt*16 + l16)*MSW + kk*32 + g*8];
                c1[0][nt] = __builtin_amdgcn_mfma_f32_16x16x32_bf16(a1[0][kk], b, c1[0][nt], 0, 0, 0);
                c1[1][nt] = __builtin_amdgcn_mfma_f32_16x16x32_bf16(a1[1][kk], b, c1[1][nt], 0, 0, 0);
            }
        __syncthreads();                               // S2: all msg reads done

        // ---- silu -> hidden overlay (stride HSW inside same buffer)
        #pragma unroll
        for (int m = 0; m < 2; ++m)
            #pragma unroll
            for (int nt = 0; nt < 4; ++nt) {
                uint2 pk;
                pk.x = (uint)f2bf(silu(c1[m][nt][0])) | ((uint)f2bf(silu(c1[m][nt][1])) << 16);
                pk.y = (uint)f2bf(silu(c1[m][nt][2])) | ((uint)f2bf(silu(c1[m][nt][3])) << 16);
                *(uint2*)&buf[(nt*16 + l16)*HSW + wv*32 + m*16 + g*4] = pk;
            }
        __syncthreads();                               // S3: hidden visible

        // ---- layer 2: C2'[out][edge], K=128
        f32x4 c2[4];
        #pragma unroll
        for (int nt = 0; nt < 4; ++nt)
            c2[nt] = (f32x4){b2v[0], b2v[1], b2v[2], b2v[3]};
        #pragma unroll
        for (int nt = 0; nt < 4; ++nt)
            #pragma unroll
            for (int kk = 0; kk < 4; ++kk) {
                short8 b = *(const short8*)&buf[(nt*16 + l16)*HSW + kk*32 + g*8];
                c2[nt] = __builtin_amdgcn_mfma_f32_16x16x32_bf16(a2[kk], b, c2[nt], 0, 0, 0);
            }

        // ---- segmented reduce over equal-dst runs, tail-lane atomics
        #pragma unroll
        for (int nt = 0; nt < 4; ++nt) {
            int d  = dvals[nt];
            int dp = __shfl_up(d, 1, 16);
            int f  = (l16 == 0 || d != dp) ? 1 : 0;
            float v0 = c2[nt][0], v1 = c2[nt][1], v2 = c2[nt][2], v3 = c2[nt][3];
            #pragma unroll
            for (int off = 1; off < 16; off <<= 1) {
                float w0 = __shfl_up(v0, off, 16);
                float w1 = __shfl_up(v1, off, 16);
                float w2 = __shfl_up(v2, off, 16);
                float w3 = __shfl_up(v3, off, 16);
                int   ff = __shfl_up(f,  off, 16);
                if (l16 >= off && !f) { v0 += w0; v1 += w1; v2 += w2; v3 += w3; }
                if (l16 >= off) f |= ff;
            }
            int dn = __shfl_down(d, 1, 16);
            if (l16 == 15 || d != dn) {
                float* p = agg + (size_t)d * 64 + wv * 16 + g * 4;
                atomicAdd(p + 0, v0);
                atomicAdd(p + 1, v1);
                atomicAdd(p + 2, v2);
                atomicAdd(p + 3, v3);
            }
        }
        __syncthreads();                               // S4: hidden reads done

        // ---- commit prefetched tile as msg layout (incl rbf + K-pad zeros)
        if (hn) {
            *(uint4*)&buf[ ea       *MSW      + cc*8] = pf0;
            *(uint4*)&buf[(32 + ea) *MSW      + cc*8] = pf1;
            *(uint4*)&buf[ ea       *MSW + 64 + cc*8] = pf2;
            *(uint4*)&buf[(32 + ea) *MSW + 64 + cc*8] = pf3;
            float u0 = pea - (float)(2*cc)   * (10.0f/15.0f);
            float u1 = pea - (float)(2*cc+1) * (10.0f/15.0f);
            *(uint*)&buf[ea*MSW + 128 + cc*2] =
                (uint)f2bf(__expf(-u0*u0*4.5f)) | ((uint)f2bf(__expf(-u1*u1*4.5f)) << 16);
            float v0 = peb - (float)(2*cc)   * (10.0f/15.0f);
            float v1 = peb - (float)(2*cc+1) * (10.0f/15.0f);
            *(uint*)&buf[(32+ea)*MSW + 128 + cc*2] =
                (uint)f2bf(__expf(-v0*v0*4.5f)) | ((uint)f2bf(__expf(-v1*v1*4.5f)) << 16);
            int ez = tid >> 2, qq = tid & 3;
            *(uint2*)&buf[ez*MSW + 144 + qq*4] = make_uint2(0u, 0u);
            #pragma unroll
            for (int nt = 0; nt < 4; ++nt) dvals[nt] = pdv[nt];
        }
    }
}

// ---------------------------------------------------------------------------
// Node kernel (MFMA): out = LN(silu([x, agg/cnt] @ uw1 + ub1) @ uw2 + ub2)
// Layer 2 decomposed so each wave owns ALL 64 channels of its own 16 nodes
// -> LayerNorm is fully in-register (16 adds + 2 shfl_xor per reduce).
// ---------------------------------------------------------------------------
__global__ __launch_bounds__(256, 4) void node_mfma(
    const ushort* __restrict__ xb,     // [NN][64] bf16
    const float*  __restrict__ agg,    // [NN][64]
    const int*    __restrict__ hist,   // [NN] combined
    const ushort* __restrict__ uw1t,   // [64][128]
    const float*  __restrict__ ub1,
    const ushort* __restrict__ uw2t,   // [64][64]
    const float*  __restrict__ ub2,
    const float*  __restrict__ lng,
    const float*  __restrict__ lnb,
    float* __restrict__ out)
{
    __shared__ ushort upd_s[64 * UPS];
    __shared__ ushort hb_s[64 * HBS];

    const int tid  = threadIdx.x;
    const int wv   = tid >> 6;
    const int lane = tid & 63;
    const int l16  = lane & 15;
    const int g    = lane >> 4;
    const int nb   = blockIdx.x * 64;

    // weight fragments: layer1 wave-split by hidden; layer2 all 64 out rows
    short8 au1[4];
    #pragma unroll
    for (int kk = 0; kk < 4; ++kk)
        au1[kk] = *(const short8*)(uw1t + (wv*16 + l16)*128 + kk*32 + g*8);
    short8 au2[4][2];
    #pragma unroll
    for (int m = 0; m < 4; ++m)
        #pragma unroll
        for (int kk = 0; kk < 2; ++kk)
            au2[m][kk] = *(const short8*)(uw2t + (m*16 + l16)*64 + kk*32 + g*8);
    float bu1[4];
    #pragma unroll
    for (int rr = 0; rr < 4; ++rr)
        bu1[rr] = ub1[wv*16 + g*4 + rr];

    // ---- stage upd = [x(bf16) | agg/cnt -> bf16]
    #pragma unroll
    for (int i = 0; i < 2; ++i) {
        int idx = i * 256 + tid, nd = (idx >> 3) & 63, cg = idx & 7;
        int n = nb + nd;
        uint4 v = make_uint4(0u, 0u, 0u, 0u);
        if (n < NN) v = *(const uint4*)(xb + (size_t)n * 64 + cg * 8);
        *(uint4*)&upd_s[nd * UPS + cg * 8] = v;
    }
    {
        int nd = tid >> 2, c16 = (tid & 3) * 16;
        int n = nb + nd;
        float rc = 0.0f;
        if (n < NN) rc = 1.0f / fmaxf((float)hist[n], 1.0f);
        const float4* ap = (const float4*)(agg + (size_t)(n < NN ? n : 0) * 64 + c16);
        #pragma unroll
        for (int j = 0; j < 4; ++j) {
            float4 v = (n < NN) ? ap[j] : make_float4(0.f, 0.f, 0.f, 0.f);
            uint2 pk;
            pk.x = (uint)f2bf(v.x * rc) | ((uint)f2bf(v.y * rc) << 16);
            pk.y = (uint)f2bf(v.z * rc) | ((uint)f2bf(v.w * rc) << 16);
            *(uint2*)&upd_s[nd * UPS + 64 + c16 + j * 4] = pk;
        }
    }
    __syncthreads();

    // ---- layer 1: C1'[h][node], K=128 (wave owns 16 hidden chans, all nodes)
    f32x4 c1[4];
    #pragma unroll
    for (int nt = 0; nt < 4; ++nt)
        c1[nt] = (f32x4){bu1[0], bu1[1], bu1[2], bu1[3]};
    #pragma unroll
    for (int nt = 0; nt < 4; ++nt)
        #pragma unroll
        for (int kk = 0; kk < 4; ++kk) {
            short8 b = *(const short8*)&upd_s[(nt*16 + l16)*UPS + kk*32 + g*8];
            c1[nt] = __builtin_amdgcn_mfma_f32_16x16x32_bf16(au1[kk], b, c1[nt], 0, 0, 0);
        }
    #pragma unroll
    for (int nt = 0; nt < 4; ++nt) {
        uint2 pk;
        pk.x = (uint)f2bf(silu(c1[nt][0])) | ((uint)f2bf(silu(c1[nt][1])) << 16);
        pk.y = (uint)f2bf(silu(c1[nt][2])) | ((uint)f2bf(silu(c1[nt][3])) << 16);
        *(uint2*)&hb_s[(nt*16 + l16)*HBS + wv*16 + g*4] = pk;
    }
    __syncthreads();

    // ---- layer 2: wave wv -> its 16 nodes (col=l16), all 64 out rows
    short8 fb[2];
    #pragma unroll
    for (int kk = 0; kk < 2; ++kk)
        fb[kk] = *(const short8*)&hb_s[(wv*16 + l16)*HBS + kk*32 + g*8];
    f32x4 c2[4];
    #pragma unroll
    for (int m = 0; m < 4; ++m) {
        c2[m] = *(const f32x4*)&ub2[m*16 + g*4];
        #pragma unroll
        for (int kk = 0; kk < 2; ++kk)
            c2[m] = __builtin_amdgcn_mfma_f32_16x16x32_bf16(au2[m][kk], fb[kk], c2[m], 0, 0, 0);
    }

    // ---- LayerNorm fully in-register: node = nb + wv*16 + l16
    float s = 0.0f;
    #pragma unroll
    for (int m = 0; m < 4; ++m)
        #pragma unroll
        for (int rr = 0; rr < 4; ++rr) s += c2[m][rr];
    s += __shfl_xor(s, 16); s += __shfl_xor(s, 32);
    float mu = s * (1.0f / 64.0f);
    float sq = 0.0f;
    #pragma unroll
    for (int m = 0; m < 4; ++m)
        #pragma unroll
        for (int rr = 0; rr < 4; ++rr) {
            float dd = c2[m][rr] - mu; sq += dd * dd;
        }
    sq += __shfl_xor(sq, 16); sq += __shfl_xor(sq, 32);
    float rst = rsqrtf(sq * (1.0f / 64.0f) + 1e-5f);

    int n = nb + wv*16 + l16;
    if (n < NN) {
        #pragma unroll
        for (int m = 0; m < 4; ++m) {
            f32x4 g4 = *(const f32x4*)&lng[m*16 + g*4];
            f32x4 b4 = *(const f32x4*)&lnb[m*16 + g*4];
            f32x4 o;
            #pragma unroll
            for (int rr = 0; rr < 4; ++rr)
                o[rr] = (c2[m][rr] - mu) * rst * g4[rr] + b4[rr];
            *(f32x4*)&out[(size_t)n * 64 + m*16 + g*4] = o;
        }
    }
}

extern "C" void kernel_launch(void* const* d_in, const int* in_sizes, int n_in,
                              void* d_out, int out_size, void* d_ws, size_t ws_size,
                              hipStream_t stream) {
    const float* x    = (const float*)d_in[0];
    const int*   ei   = (const int*)  d_in[1];
    const float* elen = (const float*)d_in[3];
    const float* mw1  = (const float*)d_in[4];
    const float* mb1  = (const float*)d_in[5];
    const float* mw2  = (const float*)d_in[6];
    const float* mb2  = (const float*)d_in[7];
    const float* uw1  = (const float*)d_in[8];
    const float* ub1  = (const float*)d_in[9];
    const float* uw2  = (const float*)d_in[10];
    const float* ub2  = (const float*)d_in[11];
    const float* lng  = (const float*)d_in[12];
    const float* lnb  = (const float*)d_in[13];

    // ws layout (bytes). Region A [0,12.8M) = prep buffers, re-zeroed into agg
    // after rank_k (prep dead by then):
    //   h2      0        .. 1,600,000
    //   starts  1,600,000.. 1,800,000
    //   bsum    1,800,000.. 1,801,024
    //   cursor2 1,900,000.. 3,500,000
    // agg       0        .. 12,800,000 (after 2nd memset)
    // hist_comb 12,800,000..13,000,000
    // ssdp      13,000,000..16,200,000
    // selen     16,200,000..19,400,000
    // xb        19,400,000..25,800,000
    // weights   25,800,000..25,890,112
    char*  ws        = (char*)d_ws;
    float* agg       = (float*)ws;
    int*   h2        = (int*)(ws + 0);
    int*   starts    = (int*)(ws + 1600000);
    int*   bsum      = (int*)(ws + 1800000);
    int*   cursor2   = (int*)(ws + 1900000);
    int*   hist_comb = (int*)(ws + 12800000);
    uint*  ssdp      = (uint*)(ws + 13000000);
    float* selen     = (float*)(ws + 16200000);
    ushort* xb   = (ushort*)(ws + 19400000);
    ushort* w1t  = (ushort*)(ws + 25800000);
    ushort* w2t  = (ushort*)(ws + 25840960);
    ushort* uw1t = (ushort*)(ws + 25857344);
    ushort* uw2t = (ushort*)(ws + 25873728);

    hipMemsetAsync(h2, 0, 1600000, stream);                 // sub-histograms
    conv_x_hist<<<3125, 256, 0, stream>>>(x, ei, xb, h2);
    conv_w<<<160, 256, 0, stream>>>(mw1, mw2, uw1, uw2, w1t, w2t, uw1t, uw2t);
    scan1<<<196, 256, 0, stream>>>(h2, hist_comb, starts, bsum);
    scan2<<<1, 256, 0, stream>>>(bsum);
    cursor_init<<<196, 256, 0, stream>>>(starts, bsum, h2, cursor2);
    rank_k<<<3125, 256, 0, stream>>>(ei, elen, cursor2, ssdp, selen);
    hipMemsetAsync(agg, 0, 12800000, stream);               // agg (prep dead now)
    edge_mfma<<<NBLK, 256, 0, stream>>>(xb, ssdp, selen, w1t, mb1, w2t, mb2, agg);
    node_mfma<<<782, 256, 0, stream>>>(xb, agg, hist_comb, uw1t, ub1, uw2t, ub2,
                                       lng, lnb, (float*)d_out);
}

// Round 14
// 336.376 us; speedup vs baseline: 3.3984x; 1.0799x over previous
//
#include <hip/hip_runtime.h>
#include <cstdint>

#define NN 50000
#define NE 800000
#define NT 12500        // edge tiles of 64
#define NBLK 1792       // edge kernel blocks (contiguous tile chunks)
#define MSW 168         // msg LDS row stride, bf16 elems (336B: 2-way banks, free)
#define HSW 136         // hidden stride, overlaid into msg buffer (272B, 2-way free)
#define UPS 136         // node upd LDS stride (bf16)
#define HBS 72          // node hidden LDS stride (bf16)

typedef short short8 __attribute__((ext_vector_type(8)));
typedef float f32x4  __attribute__((ext_vector_type(4)));

__device__ __forceinline__ ushort f2bf(float f) {
    union { float f; uint u; } v; v.f = f;
    return (ushort)((v.u + 0x7FFFu + ((v.u >> 16) & 1u)) >> 16);   // RNE
}
__device__ __forceinline__ float silu(float v) {
    return __fdividef(v, 1.0f + __expf(-v));
}

// ---- prep: fused x->bf16 + XCD-local dst histogram + weight transpose ------
__global__ __launch_bounds__(256) void conv_fused(const float* __restrict__ x,
                                                  const int* __restrict__ ei,
                                                  const float* __restrict__ mw1,
                                                  const float* __restrict__ mw2,
                                                  const float* __restrict__ uw1,
                                                  const float* __restrict__ uw2,
                                                  ushort* __restrict__ xb,
                                                  int* __restrict__ h2,
                                                  ushort* __restrict__ w1t,
                                                  ushort* __restrict__ w2t,
                                                  ushort* __restrict__ uw1t,
                                                  ushort* __restrict__ uw2t) {
    int b = blockIdx.x;
    if (b < 3125) {                              // x conversion + histogram
        int i = b * 256 + threadIdx.x;           // 800000 exact
        float4 v = ((const float4*)x)[i];
        uint2 o;
        o.x = (uint)f2bf(v.x) | ((uint)f2bf(v.y) << 16);
        o.y = (uint)f2bf(v.z) | ((uint)f2bf(v.w) << 16);
        ((uint2*)xb)[i] = o;
        atomicAdd(&h2[(b & 7) * NN + ei[NE + i]], 1);
    } else {                                     // weight transposes
        int i = (b - 3125) * 256 + threadIdx.x;  // 160*256 = 40960 exact
        if (i < 20480) {
            int h = i / 160, k = i % 160;
            w1t[i] = f2bf(k < 144 ? mw1[k * 128 + h] : 0.0f);
        } else if (i < 28672) {
            int j = i - 20480, o = j / 128, k = j % 128;
            w2t[j] = f2bf(mw2[k * 64 + o]);
        } else if (i < 36864) {
            int j = i - 28672, o = j / 128, k = j % 128;
            uw1t[j] = f2bf(uw1[k * 64 + o]);
        } else {
            int j = i - 36864, o = j / 64, k = j % 64;
            uw2t[j] = f2bf(uw2[k * 64 + o]);
        }
    }
}

// ---- counting sort by dst (XCD-partitioned) --------------------------------
__global__ __launch_bounds__(256) void scan1(const int* __restrict__ h2,
                                             int* __restrict__ hist_comb,
                                             int* __restrict__ starts,
                                             int* __restrict__ bsum) {
    __shared__ int s[256];
    int t = threadIdx.x, b = blockIdx.x, i = b * 256 + t;
    int v = 0;
    if (i < NN) {
        #pragma unroll
        for (int xg = 0; xg < 8; ++xg) v += h2[xg * NN + i];
        hist_comb[i] = v;
    }
    s[t] = v; __syncthreads();
    #pragma unroll
    for (int off = 1; off < 256; off <<= 1) {
        int a = (t >= off) ? s[t - off] : 0;
        __syncthreads();
        s[t] += a;
        __syncthreads();
    }
    if (i < NN) starts[i] = s[t] - v;            // block-local exclusive
    if (t == 255) bsum[b] = s[255];
}

// cursor_init with inline scan of the 196 block sums (replaces scan2+scan3)
__global__ __launch_bounds__(256) void cursor_init(const int* __restrict__ starts,
                                                   const int* __restrict__ bsum,
                                                   const int* __restrict__ h2,
                                                   int* __restrict__ cursor2) {
    __shared__ int sb[256];
    int t = threadIdx.x;
    int v = (t < 196) ? bsum[t] : 0;
    sb[t] = v; __syncthreads();
    #pragma unroll
    for (int off = 1; off < 256; off <<= 1) {
        int a = (t >= off) ? sb[t - off] : 0;
        __syncthreads();
        sb[t] += a;
        __syncthreads();
    }
    int base = (blockIdx.x == 0) ? 0 : sb[blockIdx.x - 1];   // exclusive prefix
    int d = blockIdx.x * 256 + t;
    if (d < NN) {
        int c = starts[d] + base;
        #pragma unroll
        for (int xg = 0; xg < 8; ++xg) {
            cursor2[xg * NN + d] = c;
            c += h2[xg * NN + d];
        }
    }
}

// emits SORTED edge data: one uint2 {src|dst<<16, elen bits} per edge
__global__ __launch_bounds__(256) void rank_k(const int* __restrict__ ei,
                                              const float* __restrict__ elen,
                                              int* __restrict__ cursor2,
                                              uint2* __restrict__ ssde) {
    int e = blockIdx.x * 256 + threadIdx.x;      // 800000 exact
    int sN = ei[e];
    int d  = ei[NE + e];
    float L = elen[e];
    int pos = atomicAdd(&cursor2[(blockIdx.x & 7) * NN + d], 1);
    ssde[pos] = make_uint2((uint)sN | ((uint)d << 16), __float_as_uint(L));
}

// ---------------------------------------------------------------------------
// Edge kernel: sorted edges, double-buffered LDS (3 barriers/tile),
// register prefetch, MFMA both layers, segmented-scan reduction.
// ---------------------------------------------------------------------------
__global__ __launch_bounds__(256, 3) void edge_mfma(
    const ushort* __restrict__ xb,     // [NN][64] bf16
    const uint2*  __restrict__ ssde,   // [NE] {src|dst<<16, elen}, sorted by dst
    const ushort* __restrict__ w1t,    // [128][160]
    const float*  __restrict__ mb1,
    const ushort* __restrict__ w2t,    // [64][128]
    const float*  __restrict__ mb2,
    float* __restrict__ agg)           // [NN][64]
{
    __shared__ ushort buf[2][64 * MSW];   // 2 x 21504 B, msg + hidden overlay

    const int tid  = threadIdx.x;
    const int wv   = tid >> 6;
    const int lane = tid & 63;
    const int l16  = lane & 15;
    const int g    = lane >> 4;

    // persistent weight fragments
    short8 a1[2][5];
    #pragma unroll
    for (int m = 0; m < 2; ++m)
        #pragma unroll
        for (int kk = 0; kk < 5; ++kk)
            a1[m][kk] = *(const short8*)(w1t + (wv*32 + m*16 + l16)*160 + kk*32 + g*8);
    short8 a2[4];
    #pragma unroll
    for (int kk = 0; kk < 4; ++kk)
        a2[kk] = *(const short8*)(w2t + (wv*16 + l16)*128 + kk*32 + g*8);
    float b1v[2][4], b2v[4];
    #pragma unroll
    for (int m = 0; m < 2; ++m)
        #pragma unroll
        for (int r = 0; r < 4; ++r)
            b1v[m][r] = mb1[wv*32 + m*16 + g*4 + r];
    #pragma unroll
    for (int r = 0; r < 4; ++r)
        b2v[r] = mb2[wv*16 + g*4 + r];

    const int q  = NT / NBLK, r = NT % NBLK;       // 6, 1748
    const int t0 = blockIdx.x < r ? blockIdx.x * (q + 1)
                                  : r * (q + 1) + (blockIdx.x - r) * q;
    const int tn = blockIdx.x < r ? q + 1 : q;

    const int ea = tid >> 3, cc = tid & 7;
    const int ez = tid >> 2, qq = tid & 3;

    // ---- prologue: stage tile t0 into buf[0] (incl rbf + K-pad zeros)
    {
        const int e0 = t0 * 64;
        uint2 sda = ssde[e0 + ea], sdb = ssde[e0 + 32 + ea];
        float ela = __uint_as_float(sda.y), elb = __uint_as_float(sdb.y);
        *(uint4*)&buf[0][ ea     *MSW      + cc*8] = *(const uint4*)(xb + (size_t)(sda.x & 0xFFFFu)*64 + cc*8);
        *(uint4*)&buf[0][(32+ea)*MSW      + cc*8] = *(const uint4*)(xb + (size_t)(sdb.x & 0xFFFFu)*64 + cc*8);
        *(uint4*)&buf[0][ ea     *MSW + 64 + cc*8] = *(const uint4*)(xb + (size_t)(sda.x >> 16)*64 + cc*8);
        *(uint4*)&buf[0][(32+ea)*MSW + 64 + cc*8] = *(const uint4*)(xb + (size_t)(sdb.x >> 16)*64 + cc*8);
        float u0 = ela - (float)(2*cc)   * (10.0f/15.0f);
        float u1 = ela - (float)(2*cc+1) * (10.0f/15.0f);
        *(uint*)&buf[0][ea*MSW + 128 + cc*2] =
            (uint)f2bf(__expf(-u0*u0*4.5f)) | ((uint)f2bf(__expf(-u1*u1*4.5f)) << 16);
        float v0 = elb - (float)(2*cc)   * (10.0f/15.0f);
        float v1 = elb - (float)(2*cc+1) * (10.0f/15.0f);
        *(uint*)&buf[0][(32+ea)*MSW + 128 + cc*2] =
            (uint)f2bf(__expf(-v0*v0*4.5f)) | ((uint)f2bf(__expf(-v1*v1*4.5f)) << 16);
        *(uint2*)&buf[0][ez*MSW + 144 + qq*4] = make_uint2(0u, 0u);
    }
    int dvals[4];
    #pragma unroll
    for (int nt = 0; nt < 4; ++nt)
        dvals[nt] = (int)(ssde[t0*64 + nt*16 + l16].x >> 16);

    int cur = 0;
    for (int tt = 0; tt < tn; ++tt) {
        __syncthreads();                               // B1: buf[cur] staged

        // ---- prefetch next tile into registers
        const bool hn = (tt + 1 < tn);
        const int e1 = (t0 + tt + 1) * 64;
        uint4 pf0, pf1, pf2, pf3; uint2 psa, psb; int pdv[4];
        if (hn) {
            psa = ssde[e1 + ea]; psb = ssde[e1 + 32 + ea];
            pf0 = *(const uint4*)(xb + (size_t)(psa.x & 0xFFFFu)*64 + cc*8);
            pf1 = *(const uint4*)(xb + (size_t)(psb.x & 0xFFFFu)*64 + cc*8);
            pf2 = *(const uint4*)(xb + (size_t)(psa.x >> 16)*64 + cc*8);
            pf3 = *(const uint4*)(xb + (size_t)(psb.x >> 16)*64 + cc*8);
            #pragma unroll
            for (int nt = 0; nt < 4; ++nt)
                pdv[nt] = (int)(ssde[e1 + nt*16 + l16].x >> 16);
        }

        // ---- layer 1: C1'[hidden][edge], K=160
        f32x4 c1[2][4];
        #pragma unroll
        for (int m = 0; m < 2; ++m)
            #pragma unroll
            for (int nt = 0; nt < 4; ++nt)
                c1[m][nt] = (f32x4){b1v[m][0], b1v[m][1], b1v[m][2], b1v[m][3]};
        #pragma unroll
        for (int nt = 0; nt < 4; ++nt)
            #pragma unroll
            for (int kk = 0; kk < 5; ++kk) {
                short8 b = *(const short8*)&buf[cur][(nt*16 + l16)*MSW + kk*32 + g*8];
                c1[0][nt] = __builtin_amdgcn_mfma_f32_16x16x32_bf16(a1[0][kk], b, c1[0][nt], 0, 0, 0);
                c1[1][nt] = __builtin_amdgcn_mfma_f32_16x16x32_bf16(a1[1][kk], b, c1[1][nt], 0, 0, 0);
            }
        __syncthreads();                               // B2: msg reads done

        // ---- silu -> hidden overlay (same buffer, stride HSW)
        #pragma unroll
        for (int m = 0; m < 2; ++m)
            #pragma unroll
            for (int nt = 0; nt < 4; ++nt) {
                uint2 pk;
                pk.x = (uint)f2bf(silu(c1[m][nt][0])) | ((uint)f2bf(silu(c1[m][nt][1])) << 16);
                pk.y = (uint)f2bf(silu(c1[m][nt][2])) | ((uint)f2bf(silu(c1[m][nt][3])) << 16);
                *(uint2*)&buf[cur][(nt*16 + l16)*HSW + wv*32 + m*16 + g*4] = pk;
            }
        __syncthreads();                               // B3: hidden visible

        // ---- layer 2: C2'[out][edge], K=128
        f32x4 c2[4];
        #pragma unroll
        for (int nt = 0; nt < 4; ++nt)
            c2[nt] = (f32x4){b2v[0], b2v[1], b2v[2], b2v[3]};
        #pragma unroll
        for (int nt = 0; nt < 4; ++nt)
            #pragma unroll
            for (int kk = 0; kk < 4; ++kk) {
                short8 b = *(const short8*)&buf[cur][(nt*16 + l16)*HSW + kk*32 + g*8];
                c2[nt] = __builtin_amdgcn_mfma_f32_16x16x32_bf16(a2[kk], b, c2[nt], 0, 0, 0);
            }

        // ---- commit prefetched tile to the OTHER buffer (no barrier needed)
        if (hn) {
            int al = cur ^ 1;
            *(uint4*)&buf[al][ ea     *MSW      + cc*8] = pf0;
            *(uint4*)&buf[al][(32+ea)*MSW      + cc*8] = pf1;
            *(uint4*)&buf[al][ ea     *MSW + 64 + cc*8] = pf2;
            *(uint4*)&buf[al][(32+ea)*MSW + 64 + cc*8] = pf3;
            float pea = __uint_as_float(psa.y), peb = __uint_as_float(psb.y);
            float u0 = pea - (float)(2*cc)   * (10.0f/15.0f);
            float u1 = pea - (float)(2*cc+1) * (10.0f/15.0f);
            *(uint*)&buf[al][ea*MSW + 128 + cc*2] =
                (uint)f2bf(__expf(-u0*u0*4.5f)) | ((uint)f2bf(__expf(-u1*u1*4.5f)) << 16);
            float v0 = peb - (float)(2*cc)   * (10.0f/15.0f);
            float v1 = peb - (float)(2*cc+1) * (10.0f/15.0f);
            *(uint*)&buf[al][(32+ea)*MSW + 128 + cc*2] =
                (uint)f2bf(__expf(-v0*v0*4.5f)) | ((uint)f2bf(__expf(-v1*v1*4.5f)) << 16);
            *(uint2*)&buf[al][ez*MSW + 144 + qq*4] = make_uint2(0u, 0u);
        }

        // ---- segmented reduce over equal-dst runs, tail-lane atomics
        #pragma unroll
        for (int nt = 0; nt < 4; ++nt) {
            int d  = dvals[nt];
            int dp = __shfl_up(d, 1, 16);
            int f  = (l16 == 0 || d != dp) ? 1 : 0;
            float v0 = c2[nt][0], v1 = c2[nt][1], v2 = c2[nt][2], v3 = c2[nt][3];
            #pragma unroll
            for (int off = 1; off < 16; off <<= 1) {
                float w0 = __shfl_up(v0, off, 16);
                float w1 = __shfl_up(v1, off, 16);
                float w2 = __shfl_up(v2, off, 16);
                float w3 = __shfl_up(v3, off, 16);
                int   ff = __shfl_up(f,  off, 16);
                if (l16 >= off && !f) { v0 += w0; v1 += w1; v2 += w2; v3 += w3; }
                if (l16 >= off) f |= ff;
            }
            int dn = __shfl_down(d, 1, 16);
            if (l16 == 15 || d != dn) {
                float* p = agg + (size_t)d * 64 + wv * 16 + g * 4;
                atomicAdd(p + 0, v0);
                atomicAdd(p + 1, v1);
                atomicAdd(p + 2, v2);
                atomicAdd(p + 3, v3);
            }
        }

        if (hn) {
            #pragma unroll
            for (int nt = 0; nt < 4; ++nt) dvals[nt] = pdv[nt];
        }
        cur ^= 1;
    }
}

// ---------------------------------------------------------------------------
// Node kernel (MFMA): out = LN(silu([x, agg/cnt] @ uw1 + ub1) @ uw2 + ub2)
// Layer 2 decomposed so each wave owns ALL 64 channels of its own 16 nodes
// -> LayerNorm fully in-register.
// ---------------------------------------------------------------------------
__global__ __launch_bounds__(256, 4) void node_mfma(
    const ushort* __restrict__ xb,     // [NN][64] bf16
    const float*  __restrict__ agg,    // [NN][64]
    const int*    __restrict__ hist,   // [NN] combined
    const ushort* __restrict__ uw1t,   // [64][128]
    const float*  __restrict__ ub1,
    const ushort* __restrict__ uw2t,   // [64][64]
    const float*  __restrict__ ub2,
    const float*  __restrict__ lng,
    const float*  __restrict__ lnb,
    float* __restrict__ out)
{
    __shared__ ushort upd_s[64 * UPS];
    __shared__ ushort hb_s[64 * HBS];

    const int tid  = threadIdx.x;
    const int wv   = tid >> 6;
    const int lane = tid & 63;
    const int l16  = lane & 15;
    const int g    = lane >> 4;
    const int nb   = blockIdx.x * 64;

    short8 au1[4];
    #pragma unroll
    for (int kk = 0; kk < 4; ++kk)
        au1[kk] = *(const short8*)(uw1t + (wv*16 + l16)*128 + kk*32 + g*8);
    short8 au2[4][2];
    #pragma unroll
    for (int m = 0; m < 4; ++m)
        #pragma unroll
        for (int kk = 0; kk < 2; ++kk)
            au2[m][kk] = *(const short8*)(uw2t + (m*16 + l16)*64 + kk*32 + g*8);
    float bu1[4];
    #pragma unroll
    for (int rr = 0; rr < 4; ++rr)
        bu1[rr] = ub1[wv*16 + g*4 + rr];

    // ---- stage upd = [x(bf16) | agg/cnt -> bf16]
    #pragma unroll
    for (int i = 0; i < 2; ++i) {
        int idx = i * 256 + tid, nd = (idx >> 3) & 63, cg = idx & 7;
        int n = nb + nd;
        uint4 v = make_uint4(0u, 0u, 0u, 0u);
        if (n < NN) v = *(const uint4*)(xb + (size_t)n * 64 + cg * 8);
        *(uint4*)&upd_s[nd * UPS + cg * 8] = v;
    }
    {
        int nd = tid >> 2, c16 = (tid & 3) * 16;
        int n = nb + nd;
        float rc = 0.0f;
        if (n < NN) rc = 1.0f / fmaxf((float)hist[n], 1.0f);
        const float4* ap = (const float4*)(agg + (size_t)(n < NN ? n : 0) * 64 + c16);
        #pragma unroll
        for (int j = 0; j < 4; ++j) {
            float4 v = (n < NN) ? ap[j] : make_float4(0.f, 0.f, 0.f, 0.f);
            uint2 pk;
            pk.x = (uint)f2bf(v.x * rc) | ((uint)f2bf(v.y * rc) << 16);
            pk.y = (uint)f2bf(v.z * rc) | ((uint)f2bf(v.w * rc) << 16);
            *(uint2*)&upd_s[nd * UPS + 64 + c16 + j * 4] = pk;
        }
    }
    __syncthreads();

    // ---- layer 1: C1'[h][node], K=128
    f32x4 c1[4];
    #pragma unroll
    for (int nt = 0; nt < 4; ++nt)
        c1[nt] = (f32x4){bu1[0], bu1[1], bu1[2], bu1[3]};
    #pragma unroll
    for (int nt = 0; nt < 4; ++nt)
        #pragma unroll
        for (int kk = 0; kk < 4; ++kk) {
            short8 b = *(const short8*)&upd_s[(nt*16 + l16)*UPS + kk*32 + g*8];
            c1[nt] = __builtin_amdgcn_mfma_f32_16x16x32_bf16(au1[kk], b, c1[nt], 0, 0, 0);
        }
    #pragma unroll
    for (int nt = 0; nt < 4; ++nt) {
        uint2 pk;
        pk.x = (uint)f2bf(silu(c1[nt][0])) | ((uint)f2bf(silu(c1[nt][1])) << 16);
        pk.y = (uint)f2bf(silu(c1[nt][2])) | ((uint)f2bf(silu(c1[nt][3])) << 16);
        *(uint2*)&hb_s[(nt*16 + l16)*HBS + wv*16 + g*4] = pk;
    }
    __syncthreads();

    // ---- layer 2: wave wv -> its 16 nodes (col=l16), all 64 out rows
    short8 fb[2];
    #pragma unroll
    for (int kk = 0; kk < 2; ++kk)
        fb[kk] = *(const short8*)&hb_s[(wv*16 + l16)*HBS + kk*32 + g*8];
    f32x4 c2[4];
    #pragma unroll
    for (int m = 0; m < 4; ++m) {
        c2[m] = *(const f32x4*)&ub2[m*16 + g*4];
        #pragma unroll
        for (int kk = 0; kk < 2; ++kk)
            c2[m] = __builtin_amdgcn_mfma_f32_16x16x32_bf16(au2[m][kk], fb[kk], c2[m], 0, 0, 0);
    }

    // ---- LayerNorm fully in-register: node = nb + wv*16 + l16
    float s = 0.0f;
    #pragma unroll
    for (int m = 0; m < 4; ++m)
        #pragma unroll
        for (int rr = 0; rr < 4; ++rr) s += c2[m][rr];
    s += __shfl_xor(s, 16); s += __shfl_xor(s, 32);
    float mu = s * (1.0f / 64.0f);
    float sq = 0.0f;
    #pragma unroll
    for (int m = 0; m < 4; ++m)
        #pragma unroll
        for (int rr = 0; rr < 4; ++rr) {
            float dd = c2[m][rr] - mu; sq += dd * dd;
        }
    sq += __shfl_xor(sq, 16); sq += __shfl_xor(sq, 32);
    float rst = rsqrtf(sq * (1.0f / 64.0f) + 1e-5f);

    int n = nb + wv*16 + l16;
    if (n < NN) {
        #pragma unroll
        for (int m = 0; m < 4; ++m) {
            f32x4 g4 = *(const f32x4*)&lng[m*16 + g*4];
            f32x4 b4 = *(const f32x4*)&lnb[m*16 + g*4];
            f32x4 o;
            #pragma unroll
            for (int rr = 0; rr < 4; ++rr)
                o[rr] = (c2[m][rr] - mu) * rst * g4[rr] + b4[rr];
            *(f32x4*)&out[(size_t)n * 64 + m*16 + g*4] = o;
        }
    }
}

extern "C" void kernel_launch(void* const* d_in, const int* in_sizes, int n_in,
                              void* d_out, int out_size, void* d_ws, size_t ws_size,
                              hipStream_t stream) {
    const float* x    = (const float*)d_in[0];
    const int*   ei   = (const int*)  d_in[1];
    const float* elen = (const float*)d_in[3];
    const float* mw1  = (const float*)d_in[4];
    const float* mb1  = (const float*)d_in[5];
    const float* mw2  = (const float*)d_in[6];
    const float* mb2  = (const float*)d_in[7];
    const float* uw1  = (const float*)d_in[8];
    const float* ub1  = (const float*)d_in[9];
    const float* uw2  = (const float*)d_in[10];
    const float* ub2  = (const float*)d_in[11];
    const float* lng  = (const float*)d_in[12];
    const float* lnb  = (const float*)d_in[13];

    // ws layout (bytes). Region A [0,12.8M) = prep buffers, re-zeroed into agg
    // after rank_k (prep buffers dead by then):
    //   h2      0        .. 1,600,000
    //   starts  1,600,000.. 1,800,000
    //   bsum    1,800,000.. 1,801,024
    //   cursor2 1,900,000.. 3,500,000
    // agg       0        .. 12,800,000 (after 2nd memset)
    // hist_comb 12,800,000..13,000,000
    // ssde      13,000,000..19,400,000 (uint2 per edge)
    // xb        19,400,000..25,800,000
    // weights   25,800,000..25,890,112
    char*  ws        = (char*)d_ws;
    float* agg       = (float*)ws;
    int*   h2        = (int*)(ws + 0);
    int*   starts    = (int*)(ws + 1600000);
    int*   bsum      = (int*)(ws + 1800000);
    int*   cursor2   = (int*)(ws + 1900000);
    int*   hist_comb = (int*)(ws + 12800000);
    uint2* ssde      = (uint2*)(ws + 13000000);
    ushort* xb   = (ushort*)(ws + 19400000);
    ushort* w1t  = (ushort*)(ws + 25800000);
    ushort* w2t  = (ushort*)(ws + 25840960);
    ushort* uw1t = (ushort*)(ws + 25857344);
    ushort* uw2t = (ushort*)(ws + 25873728);

    hipMemsetAsync(h2, 0, 1600000, stream);                 // sub-histograms
    conv_fused<<<3285, 256, 0, stream>>>(x, ei, mw1, mw2, uw1, uw2,
                                         xb, h2, w1t, w2t, uw1t, uw2t);
    scan1<<<196, 256, 0, stream>>>(h2, hist_comb, starts, bsum);
    cursor_init<<<196, 256, 0, stream>>>(starts, bsum, h2, cursor2);
    rank_k<<<3125, 256, 0, stream>>>(ei, elen, cursor2, ssde);
    hipMemsetAsync(agg, 0, 12800000, stream);               // agg (prep dead now)
    edge_mfma<<<NBLK, 256, 0, stream>>>(xb, ssde, w1t, mb1, w2t, mb2, agg);
    node_mfma<<<782, 256, 0, stream>>>(xb, agg, hist_comb, uw1t, ub1, uw2t, ub2,
                                       lng, lnb, (float*)d_out);
}